// Round 15
// baseline (250.526 us; speedup 1.0000x reference)
//
#include <hip/hip_runtime.h>

typedef float f32x4 __attribute__((ext_vector_type(4)));
typedef __bf16 bf16x8 __attribute__((ext_vector_type(8)));
typedef __bf16 bf16x4 __attribute__((ext_vector_type(4)));

// ---- workspace layout: bf16 weight-fragment region, then f32 region ----
#define WB_W1E 0
#define WB_W2E 4096
#define WB_W3E 20480
#define WB_W1N 22528
#define WB_W2N 26624
#define WB_W3N 43008
#define WB_W1D 45056
#define WB_W2D 49152
#define WB_W3D 65536
#define WB_W4D 81920
#define WB_TOTAL 83968

#define BKT_SHIFT 6
#define BKT_SZ 64

// ================= weight prep: f32 row-major [K][N] -> fragmented bf16 =================
__global__ void k_prep(const float* __restrict__ ew1, const float* __restrict__ eb1,
                       const float* __restrict__ ew2, const float* __restrict__ ew3,
                       const float* __restrict__ nw1, const float* __restrict__ nb1,
                       const float* __restrict__ nw2, const float* __restrict__ nw3,
                       const float* __restrict__ dw1, const float* __restrict__ db1,
                       const float* __restrict__ dw2, const float* __restrict__ dw3,
                       const float* __restrict__ dw4, __bf16* __restrict__ wb) {
  int gid = blockIdx.x * 256 + threadIdx.x;
  if (gid >= WB_TOTAL) return;
  const float* srcs[10] = {ew1, ew2, ew3, nw1, nw2, nw3, dw1, dw2, dw3, dw4};
  const float* brow[10] = {eb1, 0, 0, nb1, 0, 0, db1, 0, 0, 0};
  const int Ks[10] = {9, 128, 128, 5, 128, 128, 5, 128, 128, 128};
  const int Ns[10] = {128, 128, 3, 128, 128, 1, 128, 128, 128, 1};
  const int CTs[10] = {8, 8, 1, 8, 8, 1, 8, 8, 8, 1};
  const int cum[11] = {0, 4096, 20480, 22528, 26624, 43008, 45056, 49152, 65536, 81920, 83968};
  int seg = 0;
  while (gid >= cum[seg + 1]) seg++;
  int li = gid - cum[seg];
  int j = li & 7;
  int lane = (li >> 3) & 63;
  int fi = li >> 9;
  int CT = CTs[seg];
  int ct = fi % CT;
  int kt = fi / CT;
  int k = kt * 32 + ((lane >> 4) << 3) + j;  // physical k
  int n = ct * 16 + (lane & 15);
  int kl;  // logical row; -1 = zero, -2 = bias
  if (seg == 0) {
    if (k < 4) kl = k;
    else if (k >= 8 && k < 13) kl = k - 4;
    else kl = (k == 13) ? -2 : -1;
  } else if (seg == 3 || seg == 6) {
    if (k < 5) kl = k;
    else kl = (k == 5) ? -2 : -1;
  } else {
    kl = (k < Ks[seg]) ? k : -1;
  }
  float v = 0.f;
  if (n < Ns[seg]) {
    if (kl >= 0) v = srcs[seg][kl * Ns[seg] + n];
    else if (kl == -2 && brow[seg]) v = brow[seg][n];
  }
  wb[gid] = (__bf16)v;
}

// ================= sort-by-dst pipeline (one-time per launch) =================
__global__ void k_zero(const float* __restrict__ y_prev, float* __restrict__ x4,
                       int* __restrict__ bcnt, int n, int nbkt) {
  int i = blockIdx.x * 256 + threadIdx.x;
  if (i < n) x4[i] = y_prev[i];
  if (i <= nbkt) bcnt[i] = 0;
}

// bucket histogram (dst>>6): LDS hist per block, one global atomic per block-bucket
__global__ __launch_bounds__(256) void k_cntb(const int* __restrict__ dstp,
                                              int* __restrict__ bcnt, int nbkt, int E) {
  __shared__ int hist[1024];
  int tid = threadIdx.x;
  for (int t = tid; t < nbkt; t += 256) hist[t] = 0;
  __syncthreads();
  int e0 = blockIdx.x * 8192;
#pragma unroll
  for (int j = 0; j < 32; j++) {
    int e = e0 + j * 256 + tid;
    if (e < E) atomicAdd(&hist[dstp[e] >> BKT_SHIFT], 1);
  }
  __syncthreads();
  for (int t = tid; t < nbkt; t += 256) {
    int c = hist[t];
    if (c) atomicAdd(&bcnt[t], c);
  }
}

// single-block scan of bucket counts -> bstart (pristine) + cur (mutated by k_bin)
__global__ void k_scanb(const int* __restrict__ bcnt, int* __restrict__ bstart,
                        int* __restrict__ cur, int* __restrict__ rp, int nbkt, int n, int E) {
  __shared__ int sd[1024];
  int t = threadIdx.x;
  int c = (t < nbkt) ? bcnt[t] : 0;
  sd[t] = c;
  __syncthreads();
#pragma unroll
  for (int off = 1; off < 1024; off <<= 1) {
    int v = sd[t];
    int u = (t >= off) ? sd[t - off] : 0;
    __syncthreads();
    sd[t] = v + u;
    __syncthreads();
  }
  if (t < nbkt) {
    int ex = sd[t] - c;
    bstart[t] = ex;
    cur[t] = ex;
  }
  if (t == 0) {
    bstart[nbkt] = E;
    rp[n] = E;  // sentinel
  }
}

// pass1: bin edge-ids into bucket regions (block-dense-ish 4B scatter)
__global__ __launch_bounds__(256) void k_bin(const int* __restrict__ dstp, int* __restrict__ cur,
                                             int* __restrict__ eix, int nbkt, int E) {
  __shared__ int hist[1024];
  __shared__ int base[1024];
  int tid = threadIdx.x;
  for (int t = tid; t < nbkt; t += 256) hist[t] = 0;
  __syncthreads();
  int e0 = blockIdx.x * 8192;
  int b[32], lr[32];
#pragma unroll
  for (int j = 0; j < 32; j++) {
    int e = e0 + j * 256 + tid;
    if (e < E) {
      b[j] = dstp[e] >> BKT_SHIFT;
      lr[j] = atomicAdd(&hist[b[j]], 1);
    } else {
      b[j] = -1;
      lr[j] = 0;
    }
  }
  __syncthreads();
  for (int t = tid; t < nbkt; t += 256) {
    int c = hist[t];
    base[t] = c ? atomicAdd(&cur[t], c) : 0;
  }
  __syncthreads();
#pragma unroll
  for (int j = 0; j < 32; j++)
    if (b[j] >= 0) eix[base[b[j]] + lr[j]] = e0 + j * 256 + tid;
}

// pass2: one block per bucket; preload eids to regs (eix ALIASES dstS), local count +
// wave-scan -> rp/invdeg, then compute pe/ea and write sorted arrays densely.
__global__ __launch_bounds__(256) void k_build(const int* __restrict__ srcO,
                                               const int* __restrict__ dstO,
                                               const float* __restrict__ Xc,
                                               const float* __restrict__ yp,
                                               const int* __restrict__ bstart, const int* eix,
                                               int* __restrict__ srcS, int* dstS,
                                               float* __restrict__ peS, float* __restrict__ eaS,
                                               int* __restrict__ rp, float* __restrict__ invdeg,
                                               int n) {
  __shared__ int cnt[BKT_SZ];
  __shared__ int starts[BKT_SZ];
  int tid = threadIdx.x;
  int d0 = blockIdx.x << BKT_SHIFT;
  if (tid < BKT_SZ) cnt[tid] = 0;
  int gstart = bstart[blockIdx.x], gend = bstart[blockIdx.x + 1];
  __syncthreads();
  int ei[16], dd[16], rr[16];
#pragma unroll
  for (int k = 0; k < 16; k++) {
    int p = gstart + k * 256 + tid;
    ei[k] = (p < gend) ? eix[p] : -1;
  }
#pragma unroll
  for (int k = 0; k < 16; k++) {
    if (ei[k] >= 0) {
      dd[k] = dstO[ei[k]];
      rr[k] = atomicAdd(&cnt[dd[k] - d0], 1);
    }
  }
  __syncthreads();  // cnt final; all eix reads complete (drained before barrier)
  if (tid < 64) {
    int c = cnt[tid];
    int s = c;
#pragma unroll
    for (int off = 1; off < 64; off <<= 1) {
      int u = __shfl_up(s, off);
      if (tid >= off) s += u;
    }
    int ex = s - c;
    starts[tid] = ex;
    int d = d0 + tid;
    if (d < n) {
      rp[d] = gstart + ex;
      invdeg[d] = c > 0 ? 1.0f / (float)c : 0.f;
    }
  }
  __syncthreads();
#pragma unroll
  for (int k = 0; k < 16; k++) {
    int e = ei[k];
    if (e < 0) continue;
    int s = srcO[e], d = dd[k];
    float dx = Xc[d * 6 + 0] - Xc[s * 6 + 0];
    float dy = Xc[d * 6 + 1] - Xc[s * 6 + 1];
    float dz = Xc[d * 6 + 2] - Xc[s * 6 + 2];
    float nr = sqrtf(dx * dx + dy * dy + dz * dz);
    float w = yp[d] - yp[s];
    int q = gstart + starts[d - d0] + rr[k];
    srcS[q] = s;
    dstS[q] = d;
    f32x4 pv = {dx, dy, dz, nr};
    *(f32x4*)(peS + 4 * q) = pv;
    f32x4 av = {w * dx, w * dy, w * dz, 0.f};
    *(f32x4*)(eaS + 4 * q) = av;
  }
}

// ================= shared helpers =================
// act LDS: [64 rows][128 h] bf16, 256B row stride, XOR swizzle byte ^ ((row&15)<<4)
__device__ __forceinline__ int aoff(int row, int b) { return (row * 256 + b) ^ ((row & 15) << 4); }

// raw barrier: make LDS writes visible WITHOUT draining vmcnt (keeps prefetch in flight)
__device__ __forceinline__ void wg_sync() {
  asm volatile("s_waitcnt lgkmcnt(0)" ::: "memory");
  __builtin_amdgcn_s_barrier();
}

__device__ __forceinline__ bf16x4 relu_pack(f32x4 a) {
  bf16x4 p;
#pragma unroll
  for (int r = 0; r < 4; r++) {
    float v = a[r];
    p[r] = (__bf16)(v > 0.f ? v : 0.f);
  }
  return p;
}

// ================= edge pass: 4-wave WG, 64 edges/tile, n-sliced layers, NO atomics ==========
// grid 1280 (~5 WGs/CU): finer WG granularity shortens the end-of-grid solo-WG tail.
__global__ __attribute__((amdgpu_flat_work_group_size(256, 256), amdgpu_waves_per_eu(3, 4))) void
k_edge(const float* __restrict__ x4, const float* __restrict__ pe, float* __restrict__ ea,
       const int* __restrict__ src, const int* __restrict__ dstp,
       const __bf16* __restrict__ W1f, const __bf16* __restrict__ W2f,
       const __bf16* __restrict__ W3f, const float* __restrict__ b2,
       const float* __restrict__ b3, int ntiles, int E) {
  __shared__ char Ab[16384];
  __shared__ char Bb[16384];
  const int tid = threadIdx.x;
  const int l = tid & 63, w = tid >> 6;
  const int col = l & 15, krow = l >> 4;
  const int rl = w * 16 + (l >> 2), chunk = l & 3;  // staging row + 16B chunk

  // resident weight slices: wave w owns output cols n in [w*32, w*32+32)
  bf16x8 w1r[2], w2r[4][2], w3r[4];
#pragma unroll
  for (int t = 0; t < 2; t++) w1r[t] = *(const bf16x8*)(W1f + ((2 * w + t) << 9) + l * 8);
#pragma unroll
  for (int kt = 0; kt < 4; kt++)
#pragma unroll
    for (int t = 0; t < 2; t++)
      w2r[kt][t] = *(const bf16x8*)(W2f + ((kt * 8 + 2 * w + t) << 9) + l * 8);
#pragma unroll
  for (int kt = 0; kt < 4; kt++) w3r[kt] = *(const bf16x8*)(W3f + (kt << 9) + l * 8);
  f32x4 b2c[2];
#pragma unroll
  for (int t = 0; t < 2; t++) b2c[t] = *(const f32x4*)(b2 + (2 * w + t) * 16 + krow * 4);
  f32x4 b3i = {0.f, 0.f, 0.f, 0.f};
  if (krow == 0) {
    b3i[0] = b3[0];
    b3i[1] = b3[1];
    b3i[2] = b3[2];
  }

  int tile = blockIdx.x;
  if (tile >= ntiles) return;

  // prologue: load current tile's edge data (per-lane row rl, chunk role)
  int e0 = tile * 64 + rl;
  int ec = e0 < E ? e0 : E - 1;
  int cs = src[ec], cd = dstp[ec];
  f32x4 cld = {0.f, 0.f, 0.f, 0.f};
  if (chunk < 2) cld = *(const f32x4*)(((chunk == 1) ? ea : pe) + 4 * ec);
  float cxs = 0.f, cxd = 0.f;
  if (chunk == 1) {
    cxs = x4[cs];
    cxd = x4[cd];
  }

  for (;;) {
    // ---- stage input: chunk0=[disp,norm,0..], chunk1=[ea,xs,xd,1,0,0], chunk2/3=0 ----
    bf16x8 v;
#pragma unroll
    for (int q = 0; q < 8; q++) v[q] = (__bf16)0.f;
    if (chunk == 0) {
      v[0] = (__bf16)cld[0];
      v[1] = (__bf16)cld[1];
      v[2] = (__bf16)cld[2];
      v[3] = (__bf16)cld[3];
    } else if (chunk == 1) {
      v[0] = (__bf16)cld[0];
      v[1] = (__bf16)cld[1];
      v[2] = (__bf16)cld[2];
      v[3] = (__bf16)cxs;
      v[4] = (__bf16)cxd;
      v[5] = (__bf16)1.0f;
    }
    *(bf16x8*)(Ab + aoff(rl, chunk * 16)) = v;

    // prefetch stage A: next tile's indices
    int nt = tile + (int)gridDim.x;
    bool hn = nt < ntiles;
    int tc = hn ? nt : tile;
    int en = tc * 64 + rl;
    if (en >= E) en = E - 1;
    int ns = src[en], nd = dstp[en];

    wg_sync();  // A ready (input)

    // ---- layer1 (K=32, bias folded via 1-slot) ----
    f32x4 h[4][2];
#pragma unroll
    for (int c = 0; c < 4; c++)
#pragma unroll
      for (int t = 0; t < 2; t++) {
        f32x4 z = {0.f, 0.f, 0.f, 0.f};
        h[c][t] = z;
      }
    bf16x8 bb[4];
#pragma unroll
    for (int c = 0; c < 4; c++) bb[c] = *(const bf16x8*)(Ab + aoff(c * 16 + col, krow * 16));
#pragma unroll
    for (int c = 0; c < 4; c++)
#pragma unroll
      for (int t = 0; t < 2; t++)
        h[c][t] = __builtin_amdgcn_mfma_f32_16x16x32_bf16(w1r[t], bb[c], h[c][t], 0, 0, 0);
#pragma unroll
    for (int c = 0; c < 4; c++)
#pragma unroll
      for (int t = 0; t < 2; t++)
        *(bf16x4*)(Bb + aoff(c * 16 + col, (2 * w + t) * 32 + krow * 8)) = relu_pack(h[c][t]);

    wg_sync();  // B ready (h1)

    // prefetch stage B: dependent gathers (ns/nd arrived by now)
    f32x4 nld = {0.f, 0.f, 0.f, 0.f};
    if (chunk < 2) nld = *(const f32x4*)(((chunk == 1) ? ea : pe) + 4 * en);
    float nxs = 0.f, nxd = 0.f;
    if (chunk == 1) {
      nxs = x4[ns];
      nxd = x4[nd];
    }

    // ---- layer2 (128x128, resident slice) ----
#pragma unroll
    for (int c = 0; c < 4; c++)
#pragma unroll
      for (int t = 0; t < 2; t++) h[c][t] = b2c[t];
#pragma unroll
    for (int kt = 0; kt < 4; kt++) {
#pragma unroll
      for (int c = 0; c < 4; c++)
        bb[c] = *(const bf16x8*)(Bb + aoff(c * 16 + col, kt * 64 + krow * 16));
#pragma unroll
      for (int c = 0; c < 4; c++)
#pragma unroll
        for (int t = 0; t < 2; t++)
          h[c][t] = __builtin_amdgcn_mfma_f32_16x16x32_bf16(w2r[kt][t], bb[c], h[c][t], 0, 0, 0);
    }
#pragma unroll
    for (int c = 0; c < 4; c++)
#pragma unroll
      for (int t = 0; t < 2; t++)
        *(bf16x4*)(Ab + aoff(c * 16 + col, (2 * w + t) * 32 + krow * 8)) = relu_pack(h[c][t]);

    wg_sync();  // A ready (h2)

    // ---- layer3 (128 -> 3): wave w handles its own 16 edges ----
    f32x4 o = b3i;
#pragma unroll
    for (int kt = 0; kt < 4; kt++) {
      bf16x8 bq = *(const bf16x8*)(Ab + aoff(w * 16 + col, kt * 64 + krow * 16));
      o = __builtin_amdgcn_mfma_f32_16x16x32_bf16(w3r[kt], bq, o, 0, 0, 0);
    }

    // ---- epilogue: reuse this tile's staged ea via shfl (source lane 4*col+1, same wave);
    //      all lanes execute the shfl, krow0 lanes write ----
    int sl = 4 * col + 1;
    float s0 = __shfl(cld[0], sl);
    float s1 = __shfl(cld[1], sl);
    float s2 = __shfl(cld[2], sl);
    if (krow == 0) {
      int e3 = tile * 64 + w * 16 + col;
      if (e3 < E) {
        f32x4 nv;
        nv[0] = s0 + o[0];
        nv[1] = s1 + o[1];
        nv[2] = s2 + o[2];
        nv[3] = 0.f;
        *(f32x4*)(ea + 4 * e3) = nv;
      }
    }

    if (!hn) break;
    tile = nt;
    cld = nld;
    cxs = nxs;
    cxd = nxd;
  }
}

// ================= node pass: one 64-node tile per WG, fused segment-mean gather ============
__global__ __attribute__((amdgpu_flat_work_group_size(256, 256), amdgpu_waves_per_eu(3, 4))) void
k_node(float* __restrict__ x4, const float* __restrict__ Xc, const float* __restrict__ eaS,
       const int* __restrict__ rp, const float* __restrict__ invdeg,
       const __bf16* __restrict__ W1f, const __bf16* __restrict__ W2f,
       const __bf16* __restrict__ W3f, const float* __restrict__ b2,
       const float* __restrict__ b3, int n) {
  __shared__ char Ab[16384];
  __shared__ char Bb[16384];
  const int tid = threadIdx.x;
  const int l = tid & 63, w = tid >> 6;
  const int col = l & 15, krow = l >> 4;
  const int rl = w * 16 + (l >> 2), chunk = l & 3;

  bf16x8 w1r[2], w2r[4][2], w3r[4];
#pragma unroll
  for (int t = 0; t < 2; t++) w1r[t] = *(const bf16x8*)(W1f + ((2 * w + t) << 9) + l * 8);
#pragma unroll
  for (int kt = 0; kt < 4; kt++)
#pragma unroll
    for (int t = 0; t < 2; t++)
      w2r[kt][t] = *(const bf16x8*)(W2f + ((kt * 8 + 2 * w + t) << 9) + l * 8);
#pragma unroll
  for (int kt = 0; kt < 4; kt++) w3r[kt] = *(const bf16x8*)(W3f + (kt << 9) + l * 8);
  f32x4 b2c[2];
#pragma unroll
  for (int t = 0; t < 2; t++) b2c[t] = *(const f32x4*)(b2 + (2 * w + t) * 16 + krow * 4);
  float b3s = b3[0];

  int tile = blockIdx.x;
  int i0 = tile * 64 + rl;
  bool vi = i0 < n;
  int i = vi ? i0 : (n - 1);

  // fused scatter-mean: 4 lanes per node stride the contiguous eaS segment
  int ss = rp[i], se = rp[i + 1];
  float a0 = 0.f, a1 = 0.f, a2 = 0.f;
  for (int p = ss + chunk; p < se; p += 4) {
    f32x4 ev = *(const f32x4*)(eaS + 4 * p);
    a0 += ev[0];
    a1 += ev[1];
    a2 += ev[2];
  }
  a0 += __shfl_xor(a0, 1);
  a1 += __shfl_xor(a1, 1);
  a2 += __shfl_xor(a2, 1);
  a0 += __shfl_xor(a0, 2);
  a1 += __shfl_xor(a1, 2);
  a2 += __shfl_xor(a2, 2);

  bf16x8 v;
#pragma unroll
  for (int q = 0; q < 8; q++) v[q] = (__bf16)0.f;
  if (chunk == 0) {
    float x3 = Xc[i * 6 + 4];
    float xv = x4[i];
    float iv = invdeg[i];
    v[0] = (__bf16)x3;
    v[1] = (__bf16)xv;
    v[2] = (__bf16)(a0 * iv);
    v[3] = (__bf16)(a1 * iv);
    v[4] = (__bf16)(a2 * iv);
    v[5] = (__bf16)1.0f;
  }
  *(bf16x8*)(Ab + aoff(rl, chunk * 16)) = v;

  wg_sync();

  f32x4 h[4][2];
#pragma unroll
  for (int c = 0; c < 4; c++)
#pragma unroll
    for (int t = 0; t < 2; t++) {
      f32x4 z = {0.f, 0.f, 0.f, 0.f};
      h[c][t] = z;
    }
  bf16x8 bb[4];
#pragma unroll
  for (int c = 0; c < 4; c++) bb[c] = *(const bf16x8*)(Ab + aoff(c * 16 + col, krow * 16));
#pragma unroll
  for (int c = 0; c < 4; c++)
#pragma unroll
    for (int t = 0; t < 2; t++)
      h[c][t] = __builtin_amdgcn_mfma_f32_16x16x32_bf16(w1r[t], bb[c], h[c][t], 0, 0, 0);
#pragma unroll
  for (int c = 0; c < 4; c++)
#pragma unroll
    for (int t = 0; t < 2; t++)
      *(bf16x4*)(Bb + aoff(c * 16 + col, (2 * w + t) * 32 + krow * 8)) = relu_pack(h[c][t]);

  wg_sync();

#pragma unroll
  for (int c = 0; c < 4; c++)
#pragma unroll
    for (int t = 0; t < 2; t++) h[c][t] = b2c[t];
#pragma unroll
  for (int kt = 0; kt < 4; kt++) {
#pragma unroll
    for (int c = 0; c < 4; c++)
      bb[c] = *(const bf16x8*)(Bb + aoff(c * 16 + col, kt * 64 + krow * 16));
#pragma unroll
    for (int c = 0; c < 4; c++)
#pragma unroll
      for (int t = 0; t < 2; t++)
        h[c][t] = __builtin_amdgcn_mfma_f32_16x16x32_bf16(w2r[kt][t], bb[c], h[c][t], 0, 0, 0);
  }
#pragma unroll
  for (int c = 0; c < 4; c++)
#pragma unroll
    for (int t = 0; t < 2; t++)
      *(bf16x4*)(Ab + aoff(c * 16 + col, (2 * w + t) * 32 + krow * 8)) = relu_pack(h[c][t]);

  wg_sync();

  f32x4 o = {0.f, 0.f, 0.f, 0.f};
  if (krow == 0) o[0] = b3s;
#pragma unroll
  for (int kt = 0; kt < 4; kt++) {
    bf16x8 bq = *(const bf16x8*)(Ab + aoff(w * 16 + col, kt * 64 + krow * 16));
    o = __builtin_amdgcn_mfma_f32_16x16x32_bf16(w3r[kt], bq, o, 0, 0, 0);
  }

  if (krow == 0) {
    int i3 = tile * 64 + w * 16 + col;
    if (i3 < n) x4[i3] = x4[i3] + o[0];
  }
}

// ================= decoder: one 64-node tile per WG, 4 layers =================
__global__ __attribute__((amdgpu_flat_work_group_size(256, 256), amdgpu_waves_per_eu(2, 4))) void
k_dec(const float* __restrict__ x4, const float* __restrict__ Xc, const float* __restrict__ y_prev,
      const __bf16* __restrict__ W1f, const __bf16* __restrict__ W2f,
      const __bf16* __restrict__ W3f, const __bf16* __restrict__ W4f,
      const float* __restrict__ b2, const float* __restrict__ b3, const float* __restrict__ b4,
      float* __restrict__ out, int n) {
  __shared__ char Ab[16384];
  __shared__ char Bb[16384];
  const int tid = threadIdx.x;
  const int l = tid & 63, w = tid >> 6;
  const int col = l & 15, krow = l >> 4;
  const int rl = w * 16 + (l >> 2), chunk = l & 3;

  bf16x8 w1r[2], w2r[4][2], w3r[4][2], w4r[4];
#pragma unroll
  for (int t = 0; t < 2; t++) w1r[t] = *(const bf16x8*)(W1f + ((2 * w + t) << 9) + l * 8);
#pragma unroll
  for (int kt = 0; kt < 4; kt++)
#pragma unroll
    for (int t = 0; t < 2; t++) {
      w2r[kt][t] = *(const bf16x8*)(W2f + ((kt * 8 + 2 * w + t) << 9) + l * 8);
      w3r[kt][t] = *(const bf16x8*)(W3f + ((kt * 8 + 2 * w + t) << 9) + l * 8);
    }
#pragma unroll
  for (int kt = 0; kt < 4; kt++) w4r[kt] = *(const bf16x8*)(W4f + (kt << 9) + l * 8);
  f32x4 b2c[2], b3c[2];
#pragma unroll
  for (int t = 0; t < 2; t++) {
    b2c[t] = *(const f32x4*)(b2 + (2 * w + t) * 16 + krow * 4);
    b3c[t] = *(const f32x4*)(b3 + (2 * w + t) * 16 + krow * 4);
  }
  float b4s = b4[0];

  int tile = blockIdx.x;
  int i0 = tile * 64 + rl;
  bool vi = i0 < n;
  int i = vi ? i0 : (n - 1);

  bf16x8 v;
#pragma unroll
  for (int q = 0; q < 8; q++) v[q] = (__bf16)0.f;
  if (chunk == 0) {
    v[0] = (__bf16)Xc[i * 6 + 0];
    v[1] = (__bf16)Xc[i * 6 + 1];
    v[2] = (__bf16)Xc[i * 6 + 2];
    v[3] = (__bf16)Xc[i * 6 + 4];
    v[4] = (__bf16)x4[i];
    v[5] = (__bf16)1.0f;
  }
  *(bf16x8*)(Ab + aoff(rl, chunk * 16)) = v;

  wg_sync();

  f32x4 h[4][2];
  bf16x8 bb[4];
  // layer1 -> B
#pragma unroll
  for (int c = 0; c < 4; c++)
#pragma unroll
    for (int t = 0; t < 2; t++) {
      f32x4 z = {0.f, 0.f, 0.f, 0.f};
      h[c][t] = z;
    }
#pragma unroll
  for (int c = 0; c < 4; c++) bb[c] = *(const bf16x8*)(Ab + aoff(c * 16 + col, krow * 16));
#pragma unroll
  for (int c = 0; c < 4; c++)
#pragma unroll
    for (int t = 0; t < 2; t++)
      h[c][t] = __builtin_amdgcn_mfma_f32_16x16x32_bf16(w1r[t], bb[c], h[c][t], 0, 0, 0);
#pragma unroll
  for (int c = 0; c < 4; c++)
#pragma unroll
    for (int t = 0; t < 2; t++)
      *(bf16x4*)(Bb + aoff(c * 16 + col, (2 * w + t) * 32 + krow * 8)) = relu_pack(h[c][t]);

  wg_sync();

  // layer2 -> A
#pragma unroll
  for (int c = 0; c < 4; c++)
#pragma unroll
    for (int t = 0; t < 2; t++) h[c][t] = b2c[t];
#pragma unroll
  for (int kt = 0; kt < 4; kt++) {
#pragma unroll
    for (int c = 0; c < 4; c++)
      bb[c] = *(const bf16x8*)(Bb + aoff(c * 16 + col, kt * 64 + krow * 16));
#pragma unroll
    for (int c = 0; c < 4; c++)
#pragma unroll
      for (int t = 0; t < 2; t++)
        h[c][t] = __builtin_amdgcn_mfma_f32_16x16x32_bf16(w2r[kt][t], bb[c], h[c][t], 0, 0, 0);
  }
#pragma unroll
  for (int c = 0; c < 4; c++)
#pragma unroll
    for (int t = 0; t < 2; t++)
      *(bf16x4*)(Ab + aoff(c * 16 + col, (2 * w + t) * 32 + krow * 8)) = relu_pack(h[c][t]);

  wg_sync();

  // layer3 -> B
#pragma unroll
  for (int c = 0; c < 4; c++)
#pragma unroll
    for (int t = 0; t < 2; t++) h[c][t] = b3c[t];
#pragma unroll
  for (int kt = 0; kt < 4; kt++) {
#pragma unroll
    for (int c = 0; c < 4; c++)
      bb[c] = *(const bf16x8*)(Ab + aoff(c * 16 + col, kt * 64 + krow * 16));
#pragma unroll
    for (int c = 0; c < 4; c++)
#pragma unroll
      for (int t = 0; t < 2; t++)
        h[c][t] = __builtin_amdgcn_mfma_f32_16x16x32_bf16(w3r[kt][t], bb[c], h[c][t], 0, 0, 0);
  }
#pragma unroll
  for (int c = 0; c < 4; c++)
#pragma unroll
    for (int t = 0; t < 2; t++)
      *(bf16x4*)(Bb + aoff(c * 16 + col, (2 * w + t) * 32 + krow * 8)) = relu_pack(h[c][t]);

  wg_sync();

  // layer4 (128 -> 1)
  f32x4 o = {0.f, 0.f, 0.f, 0.f};
  if (krow == 0) o[0] = b4s;
#pragma unroll
  for (int kt = 0; kt < 4; kt++) {
    bf16x8 bq = *(const bf16x8*)(Bb + aoff(w * 16 + col, kt * 64 + krow * 16));
    o = __builtin_amdgcn_mfma_f32_16x16x32_bf16(w4r[kt], bq, o, 0, 0, 0);
  }

  if (krow == 0) {
    int i3 = tile * 64 + w * 16 + col;
    if (i3 < n) out[i3] = y_prev[i3] + o[0];
  }
}

// ================= host =================
extern "C" void kernel_launch(void* const* d_in, const int* in_sizes, int n_in, void* d_out,
                              int out_size, void* d_ws, size_t ws_size, hipStream_t stream) {
  const float* Xc = (const float*)d_in[0];
  const float* y_prev = (const float*)d_in[1];
  const int* edge = (const int*)d_in[2];
  const float* ew1 = (const float*)d_in[4];
  const float* eb1 = (const float*)d_in[5];
  const float* ew2 = (const float*)d_in[6];
  const float* eb2 = (const float*)d_in[7];
  const float* ew3 = (const float*)d_in[8];
  const float* eb3 = (const float*)d_in[9];
  const float* nw1 = (const float*)d_in[10];
  const float* nb1 = (const float*)d_in[11];
  const float* nw2 = (const float*)d_in[12];
  const float* nb2 = (const float*)d_in[13];
  const float* nw3 = (const float*)d_in[14];
  const float* nb3 = (const float*)d_in[15];
  const float* dw1 = (const float*)d_in[16];
  const float* db1 = (const float*)d_in[17];
  const float* dw2 = (const float*)d_in[18];
  const float* db2 = (const float*)d_in[19];
  const float* dw3 = (const float*)d_in[20];
  const float* db3 = (const float*)d_in[21];
  const float* dw4 = (const float*)d_in[22];
  const float* db4 = (const float*)d_in[23];

  int n = in_sizes[0] / 6;
  int E = in_sizes[2] / 2;
  const int* srcp = edge;
  const int* dstp = edge + E;

  __bf16* wb = (__bf16*)d_ws;
  float* fbase = (float*)((char*)d_ws + (size_t)WB_TOTAL * 2);
  size_t na = ((size_t)n + 3) & ~(size_t)3;
  float* x4 = fbase;                 // na
  float* invdeg = fbase + na;        // na
  int* rp = (int*)(fbase + 2 * na);  // na + 8 (starts, rp[n]=E)
  int* bcnt = rp + na + 8;           // 1056
  int* bstart = bcnt + 1056;         // 1056 (pristine bucket starts + sentinel)
  int* cur = bstart + 1056;          // 1024 (mutated by k_bin)
  int* srcS = cur + 1024;            // E
  int* dstS = srcS + E;              // E (aliases eix during sort build)
  float* peS = (float*)(dstS + E);   // 4*E
  float* eaS = peS + 4 * (size_t)E;  // 4*E

  size_t need = (size_t)WB_TOTAL * 2 + (3 * na + 8 + 3136 + 10 * (size_t)E) * 4;
  if (ws_size < need) return;  // workspace too small -> fail loudly

  dim3 B(256);
  int nblk = (n + 255) / 256;            // 196
  int nbkt = (n + BKT_SZ - 1) / BKT_SZ;  // 782 (must be <= 1024)
  int eblk = (E + 8191) / 8192;          // 98
  k_prep<<<dim3((WB_TOTAL + 255) / 256), B, 0, stream>>>(ew1, eb1, ew2, ew3, nw1, nb1, nw2, nw3,
                                                         dw1, db1, dw2, dw3, dw4, wb);
  k_zero<<<dim3(nblk), B, 0, stream>>>(y_prev, x4, bcnt, n, nbkt);
  k_cntb<<<dim3(eblk), B, 0, stream>>>(dstp, bcnt, nbkt, E);
  k_scanb<<<dim3(1), dim3(1024), 0, stream>>>(bcnt, bstart, cur, rp, nbkt, n, E);
  k_bin<<<dim3(eblk), B, 0, stream>>>(dstp, cur, dstS, nbkt, E);
  k_build<<<dim3(nbkt), B, 0, stream>>>(srcp, dstp, Xc, y_prev, bstart, dstS, srcS, dstS, peS,
                                        eaS, rp, invdeg, n);

  int etiles = (E + 63) / 64;
  int vtiles = (n + 63) / 64;
  int egrid = etiles < 1280 ? etiles : 1280;  // ~5 WGs/CU: short WGs shrink the solo tail
  for (int it = 0; it < 3; it++) {
    k_edge<<<dim3(egrid), B, 0, stream>>>(x4, peS, eaS, srcS, dstS, wb + WB_W1E, wb + WB_W2E,
                                          wb + WB_W3E, eb2, eb3, etiles, E);
    k_node<<<dim3(vtiles), B, 0, stream>>>(x4, Xc, eaS, rp, invdeg, wb + WB_W1N, wb + WB_W2N,
                                           wb + WB_W3N, nb2, nb3, n);
  }
  k_dec<<<dim3(vtiles), B, 0, stream>>>(x4, Xc, y_prev, wb + WB_W1D, wb + WB_W2D, wb + WB_W3D,
                                        wb + WB_W4D, db2, db3, db4, (float*)d_out, n);
}

// Round 16
// 248.908 us; speedup vs baseline: 1.0065x; 1.0065x over previous
//
#include <hip/hip_runtime.h>

typedef float f32x4 __attribute__((ext_vector_type(4)));
typedef __bf16 bf16x8 __attribute__((ext_vector_type(8)));
typedef __bf16 bf16x4 __attribute__((ext_vector_type(4)));

// ---- workspace layout: bf16 weight-fragment region, then f32 region ----
#define WB_W1E 0
#define WB_W2E 4096
#define WB_W3E 20480
#define WB_W1N 22528
#define WB_W2N 26624
#define WB_W3N 43008
#define WB_W1D 45056
#define WB_W2D 49152
#define WB_W3D 65536
#define WB_W4D 81920
#define WB_TOTAL 83968

#define BKT_SHIFT 6
#define BKT_SZ 64

// ================= weight prep: f32 row-major [K][N] -> fragmented bf16 =================
__global__ void k_prep(const float* __restrict__ ew1, const float* __restrict__ eb1,
                       const float* __restrict__ ew2, const float* __restrict__ ew3,
                       const float* __restrict__ nw1, const float* __restrict__ nb1,
                       const float* __restrict__ nw2, const float* __restrict__ nw3,
                       const float* __restrict__ dw1, const float* __restrict__ db1,
                       const float* __restrict__ dw2, const float* __restrict__ dw3,
                       const float* __restrict__ dw4, __bf16* __restrict__ wb) {
  int gid = blockIdx.x * 256 + threadIdx.x;
  if (gid >= WB_TOTAL) return;
  const float* srcs[10] = {ew1, ew2, ew3, nw1, nw2, nw3, dw1, dw2, dw3, dw4};
  const float* brow[10] = {eb1, 0, 0, nb1, 0, 0, db1, 0, 0, 0};
  const int Ks[10] = {9, 128, 128, 5, 128, 128, 5, 128, 128, 128};
  const int Ns[10] = {128, 128, 3, 128, 128, 1, 128, 128, 128, 1};
  const int CTs[10] = {8, 8, 1, 8, 8, 1, 8, 8, 8, 1};
  const int cum[11] = {0, 4096, 20480, 22528, 26624, 43008, 45056, 49152, 65536, 81920, 83968};
  int seg = 0;
  while (gid >= cum[seg + 1]) seg++;
  int li = gid - cum[seg];
  int j = li & 7;
  int lane = (li >> 3) & 63;
  int fi = li >> 9;
  int CT = CTs[seg];
  int ct = fi % CT;
  int kt = fi / CT;
  int k = kt * 32 + ((lane >> 4) << 3) + j;  // physical k
  int n = ct * 16 + (lane & 15);
  int kl;  // logical row; -1 = zero, -2 = bias
  if (seg == 0) {
    if (k < 4) kl = k;
    else if (k >= 8 && k < 13) kl = k - 4;
    else kl = (k == 13) ? -2 : -1;
  } else if (seg == 3 || seg == 6) {
    if (k < 5) kl = k;
    else kl = (k == 5) ? -2 : -1;
  } else {
    kl = (k < Ks[seg]) ? k : -1;
  }
  float v = 0.f;
  if (n < Ns[seg]) {
    if (kl >= 0) v = srcs[seg][kl * Ns[seg] + n];
    else if (kl == -2 && brow[seg]) v = brow[seg][n];
  }
  wb[gid] = (__bf16)v;
}

// ================= sort-by-dst pipeline (one-time per launch) =================
__global__ void k_zero(const float* __restrict__ y_prev, float* __restrict__ x4,
                       int* __restrict__ bcnt, int n, int nbkt) {
  int i = blockIdx.x * 256 + threadIdx.x;
  if (i < n) x4[i] = y_prev[i];
  if (i <= nbkt) bcnt[i] = 0;
}

// bucket histogram (dst>>6): LDS hist per block, one global atomic per block-bucket
__global__ __launch_bounds__(256) void k_cntb(const int* __restrict__ dstp,
                                              int* __restrict__ bcnt, int nbkt, int E) {
  __shared__ int hist[1024];
  int tid = threadIdx.x;
  for (int t = tid; t < nbkt; t += 256) hist[t] = 0;
  __syncthreads();
  int e0 = blockIdx.x * 8192;
#pragma unroll
  for (int j = 0; j < 32; j++) {
    int e = e0 + j * 256 + tid;
    if (e < E) atomicAdd(&hist[dstp[e] >> BKT_SHIFT], 1);
  }
  __syncthreads();
  for (int t = tid; t < nbkt; t += 256) {
    int c = hist[t];
    if (c) atomicAdd(&bcnt[t], c);
  }
}

// single-block scan of bucket counts -> bstart (pristine) + cur (mutated by k_bin)
__global__ void k_scanb(const int* __restrict__ bcnt, int* __restrict__ bstart,
                        int* __restrict__ cur, int* __restrict__ rp, int nbkt, int n, int E) {
  __shared__ int sd[1024];
  int t = threadIdx.x;
  int c = (t < nbkt) ? bcnt[t] : 0;
  sd[t] = c;
  __syncthreads();
#pragma unroll
  for (int off = 1; off < 1024; off <<= 1) {
    int v = sd[t];
    int u = (t >= off) ? sd[t - off] : 0;
    __syncthreads();
    sd[t] = v + u;
    __syncthreads();
  }
  if (t < nbkt) {
    int ex = sd[t] - c;
    bstart[t] = ex;
    cur[t] = ex;
  }
  if (t == 0) {
    bstart[nbkt] = E;
    rp[n] = E;  // sentinel
  }
}

// pass1: bin edge-ids into bucket regions (block-dense-ish 4B scatter)
__global__ __launch_bounds__(256) void k_bin(const int* __restrict__ dstp, int* __restrict__ cur,
                                             int* __restrict__ eix, int nbkt, int E) {
  __shared__ int hist[1024];
  __shared__ int base[1024];
  int tid = threadIdx.x;
  for (int t = tid; t < nbkt; t += 256) hist[t] = 0;
  __syncthreads();
  int e0 = blockIdx.x * 8192;
  int b[32], lr[32];
#pragma unroll
  for (int j = 0; j < 32; j++) {
    int e = e0 + j * 256 + tid;
    if (e < E) {
      b[j] = dstp[e] >> BKT_SHIFT;
      lr[j] = atomicAdd(&hist[b[j]], 1);
    } else {
      b[j] = -1;
      lr[j] = 0;
    }
  }
  __syncthreads();
  for (int t = tid; t < nbkt; t += 256) {
    int c = hist[t];
    base[t] = c ? atomicAdd(&cur[t], c) : 0;
  }
  __syncthreads();
#pragma unroll
  for (int j = 0; j < 32; j++)
    if (b[j] >= 0) eix[base[b[j]] + lr[j]] = e0 + j * 256 + tid;
}

// pass2: one block per bucket; preload eids to regs (eix ALIASES dstS), local count +
// wave-scan -> rp/invdeg, then compute pe/ea and write sorted arrays densely.
__global__ __launch_bounds__(256) void k_build(const int* __restrict__ srcO,
                                               const int* __restrict__ dstO,
                                               const float* __restrict__ Xc,
                                               const float* __restrict__ yp,
                                               const int* __restrict__ bstart, const int* eix,
                                               int* __restrict__ srcS, int* dstS,
                                               float* __restrict__ peS, float* __restrict__ eaS,
                                               int* __restrict__ rp, float* __restrict__ invdeg,
                                               int n) {
  __shared__ int cnt[BKT_SZ];
  __shared__ int starts[BKT_SZ];
  int tid = threadIdx.x;
  int d0 = blockIdx.x << BKT_SHIFT;
  if (tid < BKT_SZ) cnt[tid] = 0;
  int gstart = bstart[blockIdx.x], gend = bstart[blockIdx.x + 1];
  __syncthreads();
  int ei[16], dd[16], rr[16];
#pragma unroll
  for (int k = 0; k < 16; k++) {
    int p = gstart + k * 256 + tid;
    ei[k] = (p < gend) ? eix[p] : -1;
  }
#pragma unroll
  for (int k = 0; k < 16; k++) {
    if (ei[k] >= 0) {
      dd[k] = dstO[ei[k]];
      rr[k] = atomicAdd(&cnt[dd[k] - d0], 1);
    }
  }
  __syncthreads();  // cnt final; all eix reads complete (drained before barrier)
  if (tid < 64) {
    int c = cnt[tid];
    int s = c;
#pragma unroll
    for (int off = 1; off < 64; off <<= 1) {
      int u = __shfl_up(s, off);
      if (tid >= off) s += u;
    }
    int ex = s - c;
    starts[tid] = ex;
    int d = d0 + tid;
    if (d < n) {
      rp[d] = gstart + ex;
      invdeg[d] = c > 0 ? 1.0f / (float)c : 0.f;
    }
  }
  __syncthreads();
#pragma unroll
  for (int k = 0; k < 16; k++) {
    int e = ei[k];
    if (e < 0) continue;
    int s = srcO[e], d = dd[k];
    float dx = Xc[d * 6 + 0] - Xc[s * 6 + 0];
    float dy = Xc[d * 6 + 1] - Xc[s * 6 + 1];
    float dz = Xc[d * 6 + 2] - Xc[s * 6 + 2];
    float nr = sqrtf(dx * dx + dy * dy + dz * dz);
    float w = yp[d] - yp[s];
    int q = gstart + starts[d - d0] + rr[k];
    srcS[q] = s;
    dstS[q] = d;
    f32x4 pv = {dx, dy, dz, nr};
    *(f32x4*)(peS + 4 * q) = pv;
    f32x4 av = {w * dx, w * dy, w * dz, 0.f};
    *(f32x4*)(eaS + 4 * q) = av;
  }
}

// ================= shared helpers =================
// act LDS: [64 rows][128 h] bf16, 256B row stride, XOR swizzle byte ^ ((row&15)<<4)
// (&15 spreads column-reads over all 16 16B slots: conflicts 8.4M->3.6M, -3% time — r14)
__device__ __forceinline__ int aoff(int row, int b) { return (row * 256 + b) ^ ((row & 15) << 4); }

// raw barrier: make LDS writes visible WITHOUT draining vmcnt (keeps prefetch in flight)
__device__ __forceinline__ void wg_sync() {
  asm volatile("s_waitcnt lgkmcnt(0)" ::: "memory");
  __builtin_amdgcn_s_barrier();
}

__device__ __forceinline__ bf16x4 relu_pack(f32x4 a) {
  bf16x4 p;
#pragma unroll
  for (int r = 0; r < 4; r++) {
    float v = a[r];
    p[r] = (__bf16)(v > 0.f ? v : 0.f);
  }
  return p;
}

// ================= edge pass: 4-wave WG, 64 edges/tile, n-sliced layers, NO atomics ==========
// Best measured config (r14, 52.8us): VGPR 84, 2 WGs/CU (LDS-capped), grid 768 oversubscribed.
// Latency-bound: 3-barrier chain, per-WG tile ~5200cyc; all residency levers measured-blocked.
__global__ __attribute__((amdgpu_flat_work_group_size(256, 256), amdgpu_waves_per_eu(3, 4))) void
k_edge(const float* __restrict__ x4, const float* __restrict__ pe, float* __restrict__ ea,
       const int* __restrict__ src, const int* __restrict__ dstp,
       const __bf16* __restrict__ W1f, const __bf16* __restrict__ W2f,
       const __bf16* __restrict__ W3f, const float* __restrict__ b2,
       const float* __restrict__ b3, int ntiles, int E) {
  __shared__ char Ab[16384];
  __shared__ char Bb[16384];
  const int tid = threadIdx.x;
  const int l = tid & 63, w = tid >> 6;
  const int col = l & 15, krow = l >> 4;
  const int rl = w * 16 + (l >> 2), chunk = l & 3;  // staging row + 16B chunk

  // resident weight slices: wave w owns output cols n in [w*32, w*32+32)
  bf16x8 w1r[2], w2r[4][2], w3r[4];
#pragma unroll
  for (int t = 0; t < 2; t++) w1r[t] = *(const bf16x8*)(W1f + ((2 * w + t) << 9) + l * 8);
#pragma unroll
  for (int kt = 0; kt < 4; kt++)
#pragma unroll
    for (int t = 0; t < 2; t++)
      w2r[kt][t] = *(const bf16x8*)(W2f + ((kt * 8 + 2 * w + t) << 9) + l * 8);
#pragma unroll
  for (int kt = 0; kt < 4; kt++) w3r[kt] = *(const bf16x8*)(W3f + (kt << 9) + l * 8);
  f32x4 b2c[2];
#pragma unroll
  for (int t = 0; t < 2; t++) b2c[t] = *(const f32x4*)(b2 + (2 * w + t) * 16 + krow * 4);
  f32x4 b3i = {0.f, 0.f, 0.f, 0.f};
  if (krow == 0) {
    b3i[0] = b3[0];
    b3i[1] = b3[1];
    b3i[2] = b3[2];
  }

  int tile = blockIdx.x;
  if (tile >= ntiles) return;

  // prologue: load current tile's edge data (per-lane row rl, chunk role)
  int e0 = tile * 64 + rl;
  int ec = e0 < E ? e0 : E - 1;
  int cs = src[ec], cd = dstp[ec];
  f32x4 cld = {0.f, 0.f, 0.f, 0.f};
  if (chunk < 2) cld = *(const f32x4*)(((chunk == 1) ? ea : pe) + 4 * ec);
  float cxs = 0.f, cxd = 0.f;
  if (chunk == 1) {
    cxs = x4[cs];
    cxd = x4[cd];
  }

  for (;;) {
    // ---- stage input: chunk0=[disp,norm,0..], chunk1=[ea,xs,xd,1,0,0], chunk2/3=0 ----
    bf16x8 v;
#pragma unroll
    for (int q = 0; q < 8; q++) v[q] = (__bf16)0.f;
    if (chunk == 0) {
      v[0] = (__bf16)cld[0];
      v[1] = (__bf16)cld[1];
      v[2] = (__bf16)cld[2];
      v[3] = (__bf16)cld[3];
    } else if (chunk == 1) {
      v[0] = (__bf16)cld[0];
      v[1] = (__bf16)cld[1];
      v[2] = (__bf16)cld[2];
      v[3] = (__bf16)cxs;
      v[4] = (__bf16)cxd;
      v[5] = (__bf16)1.0f;
    }
    *(bf16x8*)(Ab + aoff(rl, chunk * 16)) = v;

    // prefetch stage A: next tile's indices
    int nt = tile + (int)gridDim.x;
    bool hn = nt < ntiles;
    int tc = hn ? nt : tile;
    int en = tc * 64 + rl;
    if (en >= E) en = E - 1;
    int ns = src[en], nd = dstp[en];

    wg_sync();  // A ready (input)

    // ---- layer1 (K=32, bias folded via 1-slot) ----
    f32x4 h[4][2];
#pragma unroll
    for (int c = 0; c < 4; c++)
#pragma unroll
      for (int t = 0; t < 2; t++) {
        f32x4 z = {0.f, 0.f, 0.f, 0.f};
        h[c][t] = z;
      }
    bf16x8 bb[4];
#pragma unroll
    for (int c = 0; c < 4; c++) bb[c] = *(const bf16x8*)(Ab + aoff(c * 16 + col, krow * 16));
#pragma unroll
    for (int c = 0; c < 4; c++)
#pragma unroll
      for (int t = 0; t < 2; t++)
        h[c][t] = __builtin_amdgcn_mfma_f32_16x16x32_bf16(w1r[t], bb[c], h[c][t], 0, 0, 0);
#pragma unroll
    for (int c = 0; c < 4; c++)
#pragma unroll
      for (int t = 0; t < 2; t++)
        *(bf16x4*)(Bb + aoff(c * 16 + col, (2 * w + t) * 32 + krow * 8)) = relu_pack(h[c][t]);

    wg_sync();  // B ready (h1)

    // prefetch stage B: dependent gathers (ns/nd arrived by now)
    f32x4 nld = {0.f, 0.f, 0.f, 0.f};
    if (chunk < 2) nld = *(const f32x4*)(((chunk == 1) ? ea : pe) + 4 * en);
    float nxs = 0.f, nxd = 0.f;
    if (chunk == 1) {
      nxs = x4[ns];
      nxd = x4[nd];
    }

    // ---- layer2 (128x128, resident slice) ----
#pragma unroll
    for (int c = 0; c < 4; c++)
#pragma unroll
      for (int t = 0; t < 2; t++) h[c][t] = b2c[t];
#pragma unroll
    for (int kt = 0; kt < 4; kt++) {
#pragma unroll
      for (int c = 0; c < 4; c++)
        bb[c] = *(const bf16x8*)(Bb + aoff(c * 16 + col, kt * 64 + krow * 16));
#pragma unroll
      for (int c = 0; c < 4; c++)
#pragma unroll
        for (int t = 0; t < 2; t++)
          h[c][t] = __builtin_amdgcn_mfma_f32_16x16x32_bf16(w2r[kt][t], bb[c], h[c][t], 0, 0, 0);
    }
#pragma unroll
    for (int c = 0; c < 4; c++)
#pragma unroll
      for (int t = 0; t < 2; t++)
        *(bf16x4*)(Ab + aoff(c * 16 + col, (2 * w + t) * 32 + krow * 8)) = relu_pack(h[c][t]);

    wg_sync();  // A ready (h2)

    // ---- layer3 (128 -> 3): wave w handles its own 16 edges ----
    f32x4 o = b3i;
#pragma unroll
    for (int kt = 0; kt < 4; kt++) {
      bf16x8 bq = *(const bf16x8*)(Ab + aoff(w * 16 + col, kt * 64 + krow * 16));
      o = __builtin_amdgcn_mfma_f32_16x16x32_bf16(w3r[kt], bq, o, 0, 0, 0);
    }

    // ---- epilogue: krow0 lane col owns edge e3; ea RMW (re-read is L2-hot: prefetch warms it)
    if (krow == 0) {
      int e3 = tile * 64 + w * 16 + col;
      if (e3 < E) {
        f32x4 oe = *(const f32x4*)(ea + 4 * e3);
        f32x4 nv;
        nv[0] = oe[0] + o[0];
        nv[1] = oe[1] + o[1];
        nv[2] = oe[2] + o[2];
        nv[3] = 0.f;
        *(f32x4*)(ea + 4 * e3) = nv;
      }
    }

    if (!hn) break;
    tile = nt;
    cld = nld;
    cxs = nxs;
    cxd = nxd;
  }
}

// ================= node pass: one 64-node tile per WG, fused segment-mean gather ============
__global__ __attribute__((amdgpu_flat_work_group_size(256, 256), amdgpu_waves_per_eu(3, 4))) void
k_node(float* __restrict__ x4, const float* __restrict__ Xc, const float* __restrict__ eaS,
       const int* __restrict__ rp, const float* __restrict__ invdeg,
       const __bf16* __restrict__ W1f, const __bf16* __restrict__ W2f,
       const __bf16* __restrict__ W3f, const float* __restrict__ b2,
       const float* __restrict__ b3, int n) {
  __shared__ char Ab[16384];
  __shared__ char Bb[16384];
  const int tid = threadIdx.x;
  const int l = tid & 63, w = tid >> 6;
  const int col = l & 15, krow = l >> 4;
  const int rl = w * 16 + (l >> 2), chunk = l & 3;

  bf16x8 w1r[2], w2r[4][2], w3r[4];
#pragma unroll
  for (int t = 0; t < 2; t++) w1r[t] = *(const bf16x8*)(W1f + ((2 * w + t) << 9) + l * 8);
#pragma unroll
  for (int kt = 0; kt < 4; kt++)
#pragma unroll
    for (int t = 0; t < 2; t++)
      w2r[kt][t] = *(const bf16x8*)(W2f + ((kt * 8 + 2 * w + t) << 9) + l * 8);
#pragma unroll
  for (int kt = 0; kt < 4; kt++) w3r[kt] = *(const bf16x8*)(W3f + (kt << 9) + l * 8);
  f32x4 b2c[2];
#pragma unroll
  for (int t = 0; t < 2; t++) b2c[t] = *(const f32x4*)(b2 + (2 * w + t) * 16 + krow * 4);
  float b3s = b3[0];

  int tile = blockIdx.x;
  int i0 = tile * 64 + rl;
  bool vi = i0 < n;
  int i = vi ? i0 : (n - 1);

  // fused scatter-mean: 4 lanes per node stride the contiguous eaS segment
  int ss = rp[i], se = rp[i + 1];
  float a0 = 0.f, a1 = 0.f, a2 = 0.f;
  for (int p = ss + chunk; p < se; p += 4) {
    f32x4 ev = *(const f32x4*)(eaS + 4 * p);
    a0 += ev[0];
    a1 += ev[1];
    a2 += ev[2];
  }
  a0 += __shfl_xor(a0, 1);
  a1 += __shfl_xor(a1, 1);
  a2 += __shfl_xor(a2, 1);
  a0 += __shfl_xor(a0, 2);
  a1 += __shfl_xor(a1, 2);
  a2 += __shfl_xor(a2, 2);

  bf16x8 v;
#pragma unroll
  for (int q = 0; q < 8; q++) v[q] = (__bf16)0.f;
  if (chunk == 0) {
    float x3 = Xc[i * 6 + 4];
    float xv = x4[i];
    float iv = invdeg[i];
    v[0] = (__bf16)x3;
    v[1] = (__bf16)xv;
    v[2] = (__bf16)(a0 * iv);
    v[3] = (__bf16)(a1 * iv);
    v[4] = (__bf16)(a2 * iv);
    v[5] = (__bf16)1.0f;
  }
  *(bf16x8*)(Ab + aoff(rl, chunk * 16)) = v;

  wg_sync();

  f32x4 h[4][2];
#pragma unroll
  for (int c = 0; c < 4; c++)
#pragma unroll
    for (int t = 0; t < 2; t++) {
      f32x4 z = {0.f, 0.f, 0.f, 0.f};
      h[c][t] = z;
    }
  bf16x8 bb[4];
#pragma unroll
  for (int c = 0; c < 4; c++) bb[c] = *(const bf16x8*)(Ab + aoff(c * 16 + col, krow * 16));
#pragma unroll
  for (int c = 0; c < 4; c++)
#pragma unroll
    for (int t = 0; t < 2; t++)
      h[c][t] = __builtin_amdgcn_mfma_f32_16x16x32_bf16(w1r[t], bb[c], h[c][t], 0, 0, 0);
#pragma unroll
  for (int c = 0; c < 4; c++)
#pragma unroll
    for (int t = 0; t < 2; t++)
      *(bf16x4*)(Bb + aoff(c * 16 + col, (2 * w + t) * 32 + krow * 8)) = relu_pack(h[c][t]);

  wg_sync();

#pragma unroll
  for (int c = 0; c < 4; c++)
#pragma unroll
    for (int t = 0; t < 2; t++) h[c][t] = b2c[t];
#pragma unroll
  for (int kt = 0; kt < 4; kt++) {
#pragma unroll
    for (int c = 0; c < 4; c++)
      bb[c] = *(const bf16x8*)(Bb + aoff(c * 16 + col, kt * 64 + krow * 16));
#pragma unroll
    for (int c = 0; c < 4; c++)
#pragma unroll
      for (int t = 0; t < 2; t++)
        h[c][t] = __builtin_amdgcn_mfma_f32_16x16x32_bf16(w2r[kt][t], bb[c], h[c][t], 0, 0, 0);
  }
#pragma unroll
  for (int c = 0; c < 4; c++)
#pragma unroll
    for (int t = 0; t < 2; t++)
      *(bf16x4*)(Ab + aoff(c * 16 + col, (2 * w + t) * 32 + krow * 8)) = relu_pack(h[c][t]);

  wg_sync();

  f32x4 o = {0.f, 0.f, 0.f, 0.f};
  if (krow == 0) o[0] = b3s;
#pragma unroll
  for (int kt = 0; kt < 4; kt++) {
    bf16x8 bq = *(const bf16x8*)(Ab + aoff(w * 16 + col, kt * 64 + krow * 16));
    o = __builtin_amdgcn_mfma_f32_16x16x32_bf16(w3r[kt], bq, o, 0, 0, 0);
  }

  if (krow == 0) {
    int i3 = tile * 64 + w * 16 + col;
    if (i3 < n) x4[i3] = x4[i3] + o[0];
  }
}

// ================= decoder: one 64-node tile per WG, 4 layers =================
__global__ __attribute__((amdgpu_flat_work_group_size(256, 256), amdgpu_waves_per_eu(2, 4))) void
k_dec(const float* __restrict__ x4, const float* __restrict__ Xc, const float* __restrict__ y_prev,
      const __bf16* __restrict__ W1f, const __bf16* __restrict__ W2f,
      const __bf16* __restrict__ W3f, const __bf16* __restrict__ W4f,
      const float* __restrict__ b2, const float* __restrict__ b3, const float* __restrict__ b4,
      float* __restrict__ out, int n) {
  __shared__ char Ab[16384];
  __shared__ char Bb[16384];
  const int tid = threadIdx.x;
  const int l = tid & 63, w = tid >> 6;
  const int col = l & 15, krow = l >> 4;
  const int rl = w * 16 + (l >> 2), chunk = l & 3;

  bf16x8 w1r[2], w2r[4][2], w3r[4][2], w4r[4];
#pragma unroll
  for (int t = 0; t < 2; t++) w1r[t] = *(const bf16x8*)(W1f + ((2 * w + t) << 9) + l * 8);
#pragma unroll
  for (int kt = 0; kt < 4; kt++)
#pragma unroll
    for (int t = 0; t < 2; t++) {
      w2r[kt][t] = *(const bf16x8*)(W2f + ((kt * 8 + 2 * w + t) << 9) + l * 8);
      w3r[kt][t] = *(const bf16x8*)(W3f + ((kt * 8 + 2 * w + t) << 9) + l * 8);
    }
#pragma unroll
  for (int kt = 0; kt < 4; kt++) w4r[kt] = *(const bf16x8*)(W4f + (kt << 9) + l * 8);
  f32x4 b2c[2], b3c[2];
#pragma unroll
  for (int t = 0; t < 2; t++) {
    b2c[t] = *(const f32x4*)(b2 + (2 * w + t) * 16 + krow * 4);
    b3c[t] = *(const f32x4*)(b3 + (2 * w + t) * 16 + krow * 4);
  }
  float b4s = b4[0];

  int tile = blockIdx.x;
  int i0 = tile * 64 + rl;
  bool vi = i0 < n;
  int i = vi ? i0 : (n - 1);

  bf16x8 v;
#pragma unroll
  for (int q = 0; q < 8; q++) v[q] = (__bf16)0.f;
  if (chunk == 0) {
    v[0] = (__bf16)Xc[i * 6 + 0];
    v[1] = (__bf16)Xc[i * 6 + 1];
    v[2] = (__bf16)Xc[i * 6 + 2];
    v[3] = (__bf16)Xc[i * 6 + 4];
    v[4] = (__bf16)x4[i];
    v[5] = (__bf16)1.0f;
  }
  *(bf16x8*)(Ab + aoff(rl, chunk * 16)) = v;

  wg_sync();

  f32x4 h[4][2];
  bf16x8 bb[4];
  // layer1 -> B
#pragma unroll
  for (int c = 0; c < 4; c++)
#pragma unroll
    for (int t = 0; t < 2; t++) {
      f32x4 z = {0.f, 0.f, 0.f, 0.f};
      h[c][t] = z;
    }
#pragma unroll
  for (int c = 0; c < 4; c++) bb[c] = *(const bf16x8*)(Ab + aoff(c * 16 + col, krow * 16));
#pragma unroll
  for (int c = 0; c < 4; c++)
#pragma unroll
    for (int t = 0; t < 2; t++)
      h[c][t] = __builtin_amdgcn_mfma_f32_16x16x32_bf16(w1r[t], bb[c], h[c][t], 0, 0, 0);
#pragma unroll
  for (int c = 0; c < 4; c++)
#pragma unroll
    for (int t = 0; t < 2; t++)
      *(bf16x4*)(Bb + aoff(c * 16 + col, (2 * w + t) * 32 + krow * 8)) = relu_pack(h[c][t]);

  wg_sync();

  // layer2 -> A
#pragma unroll
  for (int c = 0; c < 4; c++)
#pragma unroll
    for (int t = 0; t < 2; t++) h[c][t] = b2c[t];
#pragma unroll
  for (int kt = 0; kt < 4; kt++) {
#pragma unroll
    for (int c = 0; c < 4; c++)
      bb[c] = *(const bf16x8*)(Bb + aoff(c * 16 + col, kt * 64 + krow * 16));
#pragma unroll
    for (int c = 0; c < 4; c++)
#pragma unroll
      for (int t = 0; t < 2; t++)
        h[c][t] = __builtin_amdgcn_mfma_f32_16x16x32_bf16(w2r[kt][t], bb[c], h[c][t], 0, 0, 0);
  }
#pragma unroll
  for (int c = 0; c < 4; c++)
#pragma unroll
    for (int t = 0; t < 2; t++)
      *(bf16x4*)(Ab + aoff(c * 16 + col, (2 * w + t) * 32 + krow * 8)) = relu_pack(h[c][t]);

  wg_sync();

  // layer3 -> B
#pragma unroll
  for (int c = 0; c < 4; c++)
#pragma unroll
    for (int t = 0; t < 2; t++) h[c][t] = b3c[t];
#pragma unroll
  for (int kt = 0; kt < 4; kt++) {
#pragma unroll
    for (int c = 0; c < 4; c++)
      bb[c] = *(const bf16x8*)(Ab + aoff(c * 16 + col, kt * 64 + krow * 16));
#pragma unroll
    for (int c = 0; c < 4; c++)
#pragma unroll
      for (int t = 0; t < 2; t++)
        h[c][t] = __builtin_amdgcn_mfma_f32_16x16x32_bf16(w3r[kt][t], bb[c], h[c][t], 0, 0, 0);
  }
#pragma unroll
  for (int c = 0; c < 4; c++)
#pragma unroll
    for (int t = 0; t < 2; t++)
      *(bf16x4*)(Bb + aoff(c * 16 + col, (2 * w + t) * 32 + krow * 8)) = relu_pack(h[c][t]);

  wg_sync();

  // layer4 (128 -> 1)
  f32x4 o = {0.f, 0.f, 0.f, 0.f};
  if (krow == 0) o[0] = b4s;
#pragma unroll
  for (int kt = 0; kt < 4; kt++) {
    bf16x8 bq = *(const bf16x8*)(Bb + aoff(w * 16 + col, kt * 64 + krow * 16));
    o = __builtin_amdgcn_mfma_f32_16x16x32_bf16(w4r[kt], bq, o, 0, 0, 0);
  }

  if (krow == 0) {
    int i3 = tile * 64 + w * 16 + col;
    if (i3 < n) out[i3] = y_prev[i3] + o[0];
  }
}

// ================= host =================
extern "C" void kernel_launch(void* const* d_in, const int* in_sizes, int n_in, void* d_out,
                              int out_size, void* d_ws, size_t ws_size, hipStream_t stream) {
  const float* Xc = (const float*)d_in[0];
  const float* y_prev = (const float*)d_in[1];
  const int* edge = (const int*)d_in[2];
  const float* ew1 = (const float*)d_in[4];
  const float* eb1 = (const float*)d_in[5];
  const float* ew2 = (const float*)d_in[6];
  const float* eb2 = (const float*)d_in[7];
  const float* ew3 = (const float*)d_in[8];
  const float* eb3 = (const float*)d_in[9];
  const float* nw1 = (const float*)d_in[10];
  const float* nb1 = (const float*)d_in[11];
  const float* nw2 = (const float*)d_in[12];
  const float* nb2 = (const float*)d_in[13];
  const float* nw3 = (const float*)d_in[14];
  const float* nb3 = (const float*)d_in[15];
  const float* dw1 = (const float*)d_in[16];
  const float* db1 = (const float*)d_in[17];
  const float* dw2 = (const float*)d_in[18];
  const float* db2 = (const float*)d_in[19];
  const float* dw3 = (const float*)d_in[20];
  const float* db3 = (const float*)d_in[21];
  const float* dw4 = (const float*)d_in[22];
  const float* db4 = (const float*)d_in[23];

  int n = in_sizes[0] / 6;
  int E = in_sizes[2] / 2;
  const int* srcp = edge;
  const int* dstp = edge + E;

  __bf16* wb = (__bf16*)d_ws;
  float* fbase = (float*)((char*)d_ws + (size_t)WB_TOTAL * 2);
  size_t na = ((size_t)n + 3) & ~(size_t)3;
  float* x4 = fbase;                 // na
  float* invdeg = fbase + na;        // na
  int* rp = (int*)(fbase + 2 * na);  // na + 8 (starts, rp[n]=E)
  int* bcnt = rp + na + 8;           // 1056
  int* bstart = bcnt + 1056;         // 1056 (pristine bucket starts + sentinel)
  int* cur = bstart + 1056;          // 1024 (mutated by k_bin)
  int* srcS = cur + 1024;            // E
  int* dstS = srcS + E;              // E (aliases eix during sort build)
  float* peS = (float*)(dstS + E);   // 4*E
  float* eaS = peS + 4 * (size_t)E;  // 4*E

  size_t need = (size_t)WB_TOTAL * 2 + (3 * na + 8 + 3136 + 10 * (size_t)E) * 4;
  if (ws_size < need) return;  // workspace too small -> fail loudly

  dim3 B(256);
  int nblk = (n + 255) / 256;            // 196
  int nbkt = (n + BKT_SZ - 1) / BKT_SZ;  // 782 (must be <= 1024)
  int eblk = (E + 8191) / 8192;          // 98
  k_prep<<<dim3((WB_TOTAL + 255) / 256), B, 0, stream>>>(ew1, eb1, ew2, ew3, nw1, nb1, nw2, nw3,
                                                         dw1, db1, dw2, dw3, dw4, wb);
  k_zero<<<dim3(nblk), B, 0, stream>>>(y_prev, x4, bcnt, n, nbkt);
  k_cntb<<<dim3(eblk), B, 0, stream>>>(dstp, bcnt, nbkt, E);
  k_scanb<<<dim3(1), dim3(1024), 0, stream>>>(bcnt, bstart, cur, rp, nbkt, n, E);
  k_bin<<<dim3(eblk), B, 0, stream>>>(dstp, cur, dstS, nbkt, E);
  k_build<<<dim3(nbkt), B, 0, stream>>>(srcp, dstp, Xc, y_prev, bstart, dstS, srcS, dstS, peS,
                                        eaS, rp, invdeg, n);

  int etiles = (E + 63) / 64;
  int vtiles = (n + 63) / 64;
  int egrid = etiles < 768 ? etiles : 768;
  for (int it = 0; it < 3; it++) {
    k_edge<<<dim3(egrid), B, 0, stream>>>(x4, peS, eaS, srcS, dstS, wb + WB_W1E, wb + WB_W2E,
                                          wb + WB_W3E, eb2, eb3, etiles, E);
    k_node<<<dim3(vtiles), B, 0, stream>>>(x4, Xc, eaS, rp, invdeg, wb + WB_W1N, wb + WB_W2N,
                                           wb + WB_W3N, nb2, nb3, n);
  }
  k_dec<<<dim3(vtiles), B, 0, stream>>>(x4, Xc, y_prev, wb + WB_W1D, wb + WB_W2D, wb + WB_W3D,
                                        wb + WB_W4D, db2, db3, db4, (float*)d_out, n);
}

// Round 17
// 246.628 us; speedup vs baseline: 1.0158x; 1.0092x over previous
//
#include <hip/hip_runtime.h>

typedef float f32x4 __attribute__((ext_vector_type(4)));
typedef __bf16 bf16x8 __attribute__((ext_vector_type(8)));
typedef __bf16 bf16x4 __attribute__((ext_vector_type(4)));

// ---- workspace layout: bf16 weight-fragment region, then f32 region ----
#define WB_W1E 0
#define WB_W2E 4096
#define WB_W3E 20480
#define WB_W1N 22528
#define WB_W2N 26624
#define WB_W3N 43008
#define WB_W1D 45056
#define WB_W2D 49152
#define WB_W3D 65536
#define WB_W4D 81920
#define WB_TOTAL 83968

#define BKT_SHIFT 6
#define BKT_SZ 64

// ================= weight prep: f32 row-major [K][N] -> fragmented bf16 =================
__global__ void k_prep(const float* __restrict__ ew1, const float* __restrict__ eb1,
                       const float* __restrict__ ew2, const float* __restrict__ ew3,
                       const float* __restrict__ nw1, const float* __restrict__ nb1,
                       const float* __restrict__ nw2, const float* __restrict__ nw3,
                       const float* __restrict__ dw1, const float* __restrict__ db1,
                       const float* __restrict__ dw2, const float* __restrict__ dw3,
                       const float* __restrict__ dw4, __bf16* __restrict__ wb) {
  int gid = blockIdx.x * 256 + threadIdx.x;
  if (gid >= WB_TOTAL) return;
  const float* srcs[10] = {ew1, ew2, ew3, nw1, nw2, nw3, dw1, dw2, dw3, dw4};
  const float* brow[10] = {eb1, 0, 0, nb1, 0, 0, db1, 0, 0, 0};
  const int Ks[10] = {9, 128, 128, 5, 128, 128, 5, 128, 128, 128};
  const int Ns[10] = {128, 128, 3, 128, 128, 1, 128, 128, 128, 1};
  const int CTs[10] = {8, 8, 1, 8, 8, 1, 8, 8, 8, 1};
  const int cum[11] = {0, 4096, 20480, 22528, 26624, 43008, 45056, 49152, 65536, 81920, 83968};
  int seg = 0;
  while (gid >= cum[seg + 1]) seg++;
  int li = gid - cum[seg];
  int j = li & 7;
  int lane = (li >> 3) & 63;
  int fi = li >> 9;
  int CT = CTs[seg];
  int ct = fi % CT;
  int kt = fi / CT;
  int k = kt * 32 + ((lane >> 4) << 3) + j;  // physical k
  int n = ct * 16 + (lane & 15);
  int kl;  // logical row; -1 = zero, -2 = bias
  if (seg == 0) {
    if (k < 4) kl = k;
    else if (k >= 8 && k < 13) kl = k - 4;
    else kl = (k == 13) ? -2 : -1;
  } else if (seg == 3 || seg == 6) {
    if (k < 5) kl = k;
    else kl = (k == 5) ? -2 : -1;
  } else {
    kl = (k < Ks[seg]) ? k : -1;
  }
  float v = 0.f;
  if (n < Ns[seg]) {
    if (kl >= 0) v = srcs[seg][kl * Ns[seg] + n];
    else if (kl == -2 && brow[seg]) v = brow[seg][n];
  }
  wb[gid] = (__bf16)v;
}

// ================= sort-by-dst pipeline (one-time per launch) =================
__global__ void k_zero(const float* __restrict__ y_prev, float* __restrict__ x4,
                       int* __restrict__ bcnt, int n, int nbkt) {
  int i = blockIdx.x * 256 + threadIdx.x;
  if (i < n) x4[i] = y_prev[i];
  if (i <= nbkt) bcnt[i] = 0;
}

// bucket histogram (dst>>6): LDS hist per block, one global atomic per block-bucket
__global__ __launch_bounds__(256) void k_cntb(const int* __restrict__ dstp,
                                              int* __restrict__ bcnt, int nbkt, int E) {
  __shared__ int hist[1024];
  int tid = threadIdx.x;
  for (int t = tid; t < nbkt; t += 256) hist[t] = 0;
  __syncthreads();
  int e0 = blockIdx.x * 8192;
#pragma unroll
  for (int j = 0; j < 32; j++) {
    int e = e0 + j * 256 + tid;
    if (e < E) atomicAdd(&hist[dstp[e] >> BKT_SHIFT], 1);
  }
  __syncthreads();
  for (int t = tid; t < nbkt; t += 256) {
    int c = hist[t];
    if (c) atomicAdd(&bcnt[t], c);
  }
}

// single-block scan of bucket counts -> bstart (pristine) + cur (mutated by k_bin)
__global__ void k_scanb(const int* __restrict__ bcnt, int* __restrict__ bstart,
                        int* __restrict__ cur, int* __restrict__ rp, int nbkt, int n, int E) {
  __shared__ int sd[1024];
  int t = threadIdx.x;
  int c = (t < nbkt) ? bcnt[t] : 0;
  sd[t] = c;
  __syncthreads();
#pragma unroll
  for (int off = 1; off < 1024; off <<= 1) {
    int v = sd[t];
    int u = (t >= off) ? sd[t - off] : 0;
    __syncthreads();
    sd[t] = v + u;
    __syncthreads();
  }
  if (t < nbkt) {
    int ex = sd[t] - c;
    bstart[t] = ex;
    cur[t] = ex;
  }
  if (t == 0) {
    bstart[nbkt] = E;
    rp[n] = E;  // sentinel
  }
}

// pass1: bin edge-ids into bucket regions (block-dense-ish 4B scatter)
__global__ __launch_bounds__(256) void k_bin(const int* __restrict__ dstp, int* __restrict__ cur,
                                             int* __restrict__ eix, int nbkt, int E) {
  __shared__ int hist[1024];
  __shared__ int base[1024];
  int tid = threadIdx.x;
  for (int t = tid; t < nbkt; t += 256) hist[t] = 0;
  __syncthreads();
  int e0 = blockIdx.x * 8192;
  int b[32], lr[32];
#pragma unroll
  for (int j = 0; j < 32; j++) {
    int e = e0 + j * 256 + tid;
    if (e < E) {
      b[j] = dstp[e] >> BKT_SHIFT;
      lr[j] = atomicAdd(&hist[b[j]], 1);
    } else {
      b[j] = -1;
      lr[j] = 0;
    }
  }
  __syncthreads();
  for (int t = tid; t < nbkt; t += 256) {
    int c = hist[t];
    base[t] = c ? atomicAdd(&cur[t], c) : 0;
  }
  __syncthreads();
#pragma unroll
  for (int j = 0; j < 32; j++)
    if (b[j] >= 0) eix[base[b[j]] + lr[j]] = e0 + j * 256 + tid;
}

// pass2: one block per bucket; preload eids to regs (eix ALIASES dstS), local count +
// wave-scan -> rp/invdeg, then compute pe/ea and write sorted arrays densely.
__global__ __launch_bounds__(256) void k_build(const int* __restrict__ srcO,
                                               const int* __restrict__ dstO,
                                               const float* __restrict__ Xc,
                                               const float* __restrict__ yp,
                                               const int* __restrict__ bstart, const int* eix,
                                               int* __restrict__ srcS, int* dstS,
                                               float* __restrict__ peS, float* __restrict__ eaS,
                                               int* __restrict__ rp, float* __restrict__ invdeg,
                                               int n) {
  __shared__ int cnt[BKT_SZ];
  __shared__ int starts[BKT_SZ];
  int tid = threadIdx.x;
  int d0 = blockIdx.x << BKT_SHIFT;
  if (tid < BKT_SZ) cnt[tid] = 0;
  int gstart = bstart[blockIdx.x], gend = bstart[blockIdx.x + 1];
  __syncthreads();
  int ei[16], dd[16], rr[16];
#pragma unroll
  for (int k = 0; k < 16; k++) {
    int p = gstart + k * 256 + tid;
    ei[k] = (p < gend) ? eix[p] : -1;
  }
#pragma unroll
  for (int k = 0; k < 16; k++) {
    if (ei[k] >= 0) {
      dd[k] = dstO[ei[k]];
      rr[k] = atomicAdd(&cnt[dd[k] - d0], 1);
    }
  }
  __syncthreads();  // cnt final; all eix reads complete (drained before barrier)
  if (tid < 64) {
    int c = cnt[tid];
    int s = c;
#pragma unroll
    for (int off = 1; off < 64; off <<= 1) {
      int u = __shfl_up(s, off);
      if (tid >= off) s += u;
    }
    int ex = s - c;
    starts[tid] = ex;
    int d = d0 + tid;
    if (d < n) {
      rp[d] = gstart + ex;
      invdeg[d] = c > 0 ? 1.0f / (float)c : 0.f;
    }
  }
  __syncthreads();
#pragma unroll
  for (int k = 0; k < 16; k++) {
    int e = ei[k];
    if (e < 0) continue;
    int s = srcO[e], d = dd[k];
    float dx = Xc[d * 6 + 0] - Xc[s * 6 + 0];
    float dy = Xc[d * 6 + 1] - Xc[s * 6 + 1];
    float dz = Xc[d * 6 + 2] - Xc[s * 6 + 2];
    float nr = sqrtf(dx * dx + dy * dy + dz * dz);
    float w = yp[d] - yp[s];
    int q = gstart + starts[d - d0] + rr[k];
    srcS[q] = s;
    dstS[q] = d;
    f32x4 pv = {dx, dy, dz, nr};
    *(f32x4*)(peS + 4 * q) = pv;
    f32x4 av = {w * dx, w * dy, w * dz, 0.f};
    *(f32x4*)(eaS + 4 * q) = av;
  }
}

// ================= shared helpers =================
// act LDS: [64 rows][128 h] bf16, 256B row stride, XOR swizzle byte ^ ((row&15)<<4)
__device__ __forceinline__ int aoff(int row, int b) { return (row * 256 + b) ^ ((row & 15) << 4); }

// raw barrier: make LDS writes visible WITHOUT draining vmcnt (keeps prefetch in flight)
__device__ __forceinline__ void wg_sync() {
  asm volatile("s_waitcnt lgkmcnt(0)" ::: "memory");
  __builtin_amdgcn_s_barrier();
}

__device__ __forceinline__ bf16x4 relu_pack(f32x4 a) {
  bf16x4 p;
#pragma unroll
  for (int r = 0; r < 4; r++) {
    float v = a[r];
    p[r] = (__bf16)(v > 0.f ? v : 0.f);
  }
  return p;
}

// ================= edge pass: 4-wave WG, 64 edges/tile, n-sliced layers, NO atomics ==========
// r14 best structure + T5 s_setprio around MFMA clusters: 2 independent phase-drifted WGs/CU
// give the scheduler arbitration diversity (attn-like regime where setprio measured +4-7%).
__global__ __attribute__((amdgpu_flat_work_group_size(256, 256), amdgpu_waves_per_eu(3, 4))) void
k_edge(const float* __restrict__ x4, const float* __restrict__ pe, float* __restrict__ ea,
       const int* __restrict__ src, const int* __restrict__ dstp,
       const __bf16* __restrict__ W1f, const __bf16* __restrict__ W2f,
       const __bf16* __restrict__ W3f, const float* __restrict__ b2,
       const float* __restrict__ b3, int ntiles, int E) {
  __shared__ char Ab[16384];
  __shared__ char Bb[16384];
  const int tid = threadIdx.x;
  const int l = tid & 63, w = tid >> 6;
  const int col = l & 15, krow = l >> 4;
  const int rl = w * 16 + (l >> 2), chunk = l & 3;  // staging row + 16B chunk

  // resident weight slices: wave w owns output cols n in [w*32, w*32+32)
  bf16x8 w1r[2], w2r[4][2], w3r[4];
#pragma unroll
  for (int t = 0; t < 2; t++) w1r[t] = *(const bf16x8*)(W1f + ((2 * w + t) << 9) + l * 8);
#pragma unroll
  for (int kt = 0; kt < 4; kt++)
#pragma unroll
    for (int t = 0; t < 2; t++)
      w2r[kt][t] = *(const bf16x8*)(W2f + ((kt * 8 + 2 * w + t) << 9) + l * 8);
#pragma unroll
  for (int kt = 0; kt < 4; kt++) w3r[kt] = *(const bf16x8*)(W3f + (kt << 9) + l * 8);
  f32x4 b2c[2];
#pragma unroll
  for (int t = 0; t < 2; t++) b2c[t] = *(const f32x4*)(b2 + (2 * w + t) * 16 + krow * 4);
  f32x4 b3i = {0.f, 0.f, 0.f, 0.f};
  if (krow == 0) {
    b3i[0] = b3[0];
    b3i[1] = b3[1];
    b3i[2] = b3[2];
  }

  int tile = blockIdx.x;
  if (tile >= ntiles) return;

  // prologue: load current tile's edge data (per-lane row rl, chunk role)
  int e0 = tile * 64 + rl;
  int ec = e0 < E ? e0 : E - 1;
  int cs = src[ec], cd = dstp[ec];
  f32x4 cld = {0.f, 0.f, 0.f, 0.f};
  if (chunk < 2) cld = *(const f32x4*)(((chunk == 1) ? ea : pe) + 4 * ec);
  float cxs = 0.f, cxd = 0.f;
  if (chunk == 1) {
    cxs = x4[cs];
    cxd = x4[cd];
  }

  for (;;) {
    // ---- stage input: chunk0=[disp,norm,0..], chunk1=[ea,xs,xd,1,0,0], chunk2/3=0 ----
    bf16x8 v;
#pragma unroll
    for (int q = 0; q < 8; q++) v[q] = (__bf16)0.f;
    if (chunk == 0) {
      v[0] = (__bf16)cld[0];
      v[1] = (__bf16)cld[1];
      v[2] = (__bf16)cld[2];
      v[3] = (__bf16)cld[3];
    } else if (chunk == 1) {
      v[0] = (__bf16)cld[0];
      v[1] = (__bf16)cld[1];
      v[2] = (__bf16)cld[2];
      v[3] = (__bf16)cxs;
      v[4] = (__bf16)cxd;
      v[5] = (__bf16)1.0f;
    }
    *(bf16x8*)(Ab + aoff(rl, chunk * 16)) = v;

    // prefetch stage A: next tile's indices
    int nt = tile + (int)gridDim.x;
    bool hn = nt < ntiles;
    int tc = hn ? nt : tile;
    int en = tc * 64 + rl;
    if (en >= E) en = E - 1;
    int ns = src[en], nd = dstp[en];

    wg_sync();  // A ready (input)

    // ---- layer1 (K=32, bias folded via 1-slot) ----
    f32x4 h[4][2];
#pragma unroll
    for (int c = 0; c < 4; c++)
#pragma unroll
      for (int t = 0; t < 2; t++) {
        f32x4 z = {0.f, 0.f, 0.f, 0.f};
        h[c][t] = z;
      }
    bf16x8 bb[4];
#pragma unroll
    for (int c = 0; c < 4; c++) bb[c] = *(const bf16x8*)(Ab + aoff(c * 16 + col, krow * 16));
    __builtin_amdgcn_s_setprio(1);
#pragma unroll
    for (int c = 0; c < 4; c++)
#pragma unroll
      for (int t = 0; t < 2; t++)
        h[c][t] = __builtin_amdgcn_mfma_f32_16x16x32_bf16(w1r[t], bb[c], h[c][t], 0, 0, 0);
    __builtin_amdgcn_s_setprio(0);
#pragma unroll
    for (int c = 0; c < 4; c++)
#pragma unroll
      for (int t = 0; t < 2; t++)
        *(bf16x4*)(Bb + aoff(c * 16 + col, (2 * w + t) * 32 + krow * 8)) = relu_pack(h[c][t]);

    wg_sync();  // B ready (h1)

    // prefetch stage B: dependent gathers (ns/nd arrived by now)
    f32x4 nld = {0.f, 0.f, 0.f, 0.f};
    if (chunk < 2) nld = *(const f32x4*)(((chunk == 1) ? ea : pe) + 4 * en);
    float nxs = 0.f, nxd = 0.f;
    if (chunk == 1) {
      nxs = x4[ns];
      nxd = x4[nd];
    }

    // ---- layer2 (128x128, resident slice) ----
#pragma unroll
    for (int c = 0; c < 4; c++)
#pragma unroll
      for (int t = 0; t < 2; t++) h[c][t] = b2c[t];
    __builtin_amdgcn_s_setprio(1);
#pragma unroll
    for (int kt = 0; kt < 4; kt++) {
#pragma unroll
      for (int c = 0; c < 4; c++)
        bb[c] = *(const bf16x8*)(Bb + aoff(c * 16 + col, kt * 64 + krow * 16));
#pragma unroll
      for (int c = 0; c < 4; c++)
#pragma unroll
        for (int t = 0; t < 2; t++)
          h[c][t] = __builtin_amdgcn_mfma_f32_16x16x32_bf16(w2r[kt][t], bb[c], h[c][t], 0, 0, 0);
    }
    __builtin_amdgcn_s_setprio(0);
#pragma unroll
    for (int c = 0; c < 4; c++)
#pragma unroll
      for (int t = 0; t < 2; t++)
        *(bf16x4*)(Ab + aoff(c * 16 + col, (2 * w + t) * 32 + krow * 8)) = relu_pack(h[c][t]);

    wg_sync();  // A ready (h2)

    // ---- layer3 (128 -> 3): wave w handles its own 16 edges ----
    f32x4 o = b3i;
    __builtin_amdgcn_s_setprio(1);
#pragma unroll
    for (int kt = 0; kt < 4; kt++) {
      bf16x8 bq = *(const bf16x8*)(Ab + aoff(w * 16 + col, kt * 64 + krow * 16));
      o = __builtin_amdgcn_mfma_f32_16x16x32_bf16(w3r[kt], bq, o, 0, 0, 0);
    }
    __builtin_amdgcn_s_setprio(0);

    // ---- epilogue: krow0 lane col owns edge e3; ea RMW (re-read is L2-hot) ----
    if (krow == 0) {
      int e3 = tile * 64 + w * 16 + col;
      if (e3 < E) {
        f32x4 oe = *(const f32x4*)(ea + 4 * e3);
        f32x4 nv;
        nv[0] = oe[0] + o[0];
        nv[1] = oe[1] + o[1];
        nv[2] = oe[2] + o[2];
        nv[3] = 0.f;
        *(f32x4*)(ea + 4 * e3) = nv;
      }
    }

    if (!hn) break;
    tile = nt;
    cld = nld;
    cxs = nxs;
    cxd = nxd;
  }
}

// ================= node pass: one 64-node tile per WG, fused segment-mean gather ============
__global__ __attribute__((amdgpu_flat_work_group_size(256, 256), amdgpu_waves_per_eu(3, 4))) void
k_node(float* __restrict__ x4, const float* __restrict__ Xc, const float* __restrict__ eaS,
       const int* __restrict__ rp, const float* __restrict__ invdeg,
       const __bf16* __restrict__ W1f, const __bf16* __restrict__ W2f,
       const __bf16* __restrict__ W3f, const float* __restrict__ b2,
       const float* __restrict__ b3, int n) {
  __shared__ char Ab[16384];
  __shared__ char Bb[16384];
  const int tid = threadIdx.x;
  const int l = tid & 63, w = tid >> 6;
  const int col = l & 15, krow = l >> 4;
  const int rl = w * 16 + (l >> 2), chunk = l & 3;

  bf16x8 w1r[2], w2r[4][2], w3r[4];
#pragma unroll
  for (int t = 0; t < 2; t++) w1r[t] = *(const bf16x8*)(W1f + ((2 * w + t) << 9) + l * 8);
#pragma unroll
  for (int kt = 0; kt < 4; kt++)
#pragma unroll
    for (int t = 0; t < 2; t++)
      w2r[kt][t] = *(const bf16x8*)(W2f + ((kt * 8 + 2 * w + t) << 9) + l * 8);
#pragma unroll
  for (int kt = 0; kt < 4; kt++) w3r[kt] = *(const bf16x8*)(W3f + (kt << 9) + l * 8);
  f32x4 b2c[2];
#pragma unroll
  for (int t = 0; t < 2; t++) b2c[t] = *(const f32x4*)(b2 + (2 * w + t) * 16 + krow * 4);
  float b3s = b3[0];

  int tile = blockIdx.x;
  int i0 = tile * 64 + rl;
  bool vi = i0 < n;
  int i = vi ? i0 : (n - 1);

  // fused scatter-mean: 4 lanes per node stride the contiguous eaS segment
  int ss = rp[i], se = rp[i + 1];
  float a0 = 0.f, a1 = 0.f, a2 = 0.f;
  for (int p = ss + chunk; p < se; p += 4) {
    f32x4 ev = *(const f32x4*)(eaS + 4 * p);
    a0 += ev[0];
    a1 += ev[1];
    a2 += ev[2];
  }
  a0 += __shfl_xor(a0, 1);
  a1 += __shfl_xor(a1, 1);
  a2 += __shfl_xor(a2, 1);
  a0 += __shfl_xor(a0, 2);
  a1 += __shfl_xor(a1, 2);
  a2 += __shfl_xor(a2, 2);

  bf16x8 v;
#pragma unroll
  for (int q = 0; q < 8; q++) v[q] = (__bf16)0.f;
  if (chunk == 0) {
    float x3 = Xc[i * 6 + 4];
    float xv = x4[i];
    float iv = invdeg[i];
    v[0] = (__bf16)x3;
    v[1] = (__bf16)xv;
    v[2] = (__bf16)(a0 * iv);
    v[3] = (__bf16)(a1 * iv);
    v[4] = (__bf16)(a2 * iv);
    v[5] = (__bf16)1.0f;
  }
  *(bf16x8*)(Ab + aoff(rl, chunk * 16)) = v;

  wg_sync();

  f32x4 h[4][2];
#pragma unroll
  for (int c = 0; c < 4; c++)
#pragma unroll
    for (int t = 0; t < 2; t++) {
      f32x4 z = {0.f, 0.f, 0.f, 0.f};
      h[c][t] = z;
    }
  bf16x8 bb[4];
#pragma unroll
  for (int c = 0; c < 4; c++) bb[c] = *(const bf16x8*)(Ab + aoff(c * 16 + col, krow * 16));
#pragma unroll
  for (int c = 0; c < 4; c++)
#pragma unroll
    for (int t = 0; t < 2; t++)
      h[c][t] = __builtin_amdgcn_mfma_f32_16x16x32_bf16(w1r[t], bb[c], h[c][t], 0, 0, 0);
#pragma unroll
  for (int c = 0; c < 4; c++)
#pragma unroll
    for (int t = 0; t < 2; t++)
      *(bf16x4*)(Bb + aoff(c * 16 + col, (2 * w + t) * 32 + krow * 8)) = relu_pack(h[c][t]);

  wg_sync();

#pragma unroll
  for (int c = 0; c < 4; c++)
#pragma unroll
    for (int t = 0; t < 2; t++) h[c][t] = b2c[t];
#pragma unroll
  for (int kt = 0; kt < 4; kt++) {
#pragma unroll
    for (int c = 0; c < 4; c++)
      bb[c] = *(const bf16x8*)(Bb + aoff(c * 16 + col, kt * 64 + krow * 16));
#pragma unroll
    for (int c = 0; c < 4; c++)
#pragma unroll
      for (int t = 0; t < 2; t++)
        h[c][t] = __builtin_amdgcn_mfma_f32_16x16x32_bf16(w2r[kt][t], bb[c], h[c][t], 0, 0, 0);
  }
#pragma unroll
  for (int c = 0; c < 4; c++)
#pragma unroll
    for (int t = 0; t < 2; t++)
      *(bf16x4*)(Ab + aoff(c * 16 + col, (2 * w + t) * 32 + krow * 8)) = relu_pack(h[c][t]);

  wg_sync();

  f32x4 o = {0.f, 0.f, 0.f, 0.f};
  if (krow == 0) o[0] = b3s;
#pragma unroll
  for (int kt = 0; kt < 4; kt++) {
    bf16x8 bq = *(const bf16x8*)(Ab + aoff(w * 16 + col, kt * 64 + krow * 16));
    o = __builtin_amdgcn_mfma_f32_16x16x32_bf16(w3r[kt], bq, o, 0, 0, 0);
  }

  if (krow == 0) {
    int i3 = tile * 64 + w * 16 + col;
    if (i3 < n) x4[i3] = x4[i3] + o[0];
  }
}

// ================= decoder: one 64-node tile per WG, 4 layers =================
__global__ __attribute__((amdgpu_flat_work_group_size(256, 256), amdgpu_waves_per_eu(2, 4))) void
k_dec(const float* __restrict__ x4, const float* __restrict__ Xc, const float* __restrict__ y_prev,
      const __bf16* __restrict__ W1f, const __bf16* __restrict__ W2f,
      const __bf16* __restrict__ W3f, const __bf16* __restrict__ W4f,
      const float* __restrict__ b2, const float* __restrict__ b3, const float* __restrict__ b4,
      float* __restrict__ out, int n) {
  __shared__ char Ab[16384];
  __shared__ char Bb[16384];
  const int tid = threadIdx.x;
  const int l = tid & 63, w = tid >> 6;
  const int col = l & 15, krow = l >> 4;
  const int rl = w * 16 + (l >> 2), chunk = l & 3;

  bf16x8 w1r[2], w2r[4][2], w3r[4][2], w4r[4];
#pragma unroll
  for (int t = 0; t < 2; t++) w1r[t] = *(const bf16x8*)(W1f + ((2 * w + t) << 9) + l * 8);
#pragma unroll
  for (int kt = 0; kt < 4; kt++)
#pragma unroll
    for (int t = 0; t < 2; t++) {
      w2r[kt][t] = *(const bf16x8*)(W2f + ((kt * 8 + 2 * w + t) << 9) + l * 8);
      w3r[kt][t] = *(const bf16x8*)(W3f + ((kt * 8 + 2 * w + t) << 9) + l * 8);
    }
#pragma unroll
  for (int kt = 0; kt < 4; kt++) w4r[kt] = *(const bf16x8*)(W4f + (kt << 9) + l * 8);
  f32x4 b2c[2], b3c[2];
#pragma unroll
  for (int t = 0; t < 2; t++) {
    b2c[t] = *(const f32x4*)(b2 + (2 * w + t) * 16 + krow * 4);
    b3c[t] = *(const f32x4*)(b3 + (2 * w + t) * 16 + krow * 4);
  }
  float b4s = b4[0];

  int tile = blockIdx.x;
  int i0 = tile * 64 + rl;
  bool vi = i0 < n;
  int i = vi ? i0 : (n - 1);

  bf16x8 v;
#pragma unroll
  for (int q = 0; q < 8; q++) v[q] = (__bf16)0.f;
  if (chunk == 0) {
    v[0] = (__bf16)Xc[i * 6 + 0];
    v[1] = (__bf16)Xc[i * 6 + 1];
    v[2] = (__bf16)Xc[i * 6 + 2];
    v[3] = (__bf16)Xc[i * 6 + 4];
    v[4] = (__bf16)x4[i];
    v[5] = (__bf16)1.0f;
  }
  *(bf16x8*)(Ab + aoff(rl, chunk * 16)) = v;

  wg_sync();

  f32x4 h[4][2];
  bf16x8 bb[4];
  // layer1 -> B
#pragma unroll
  for (int c = 0; c < 4; c++)
#pragma unroll
    for (int t = 0; t < 2; t++) {
      f32x4 z = {0.f, 0.f, 0.f, 0.f};
      h[c][t] = z;
    }
#pragma unroll
  for (int c = 0; c < 4; c++) bb[c] = *(const bf16x8*)(Ab + aoff(c * 16 + col, krow * 16));
#pragma unroll
  for (int c = 0; c < 4; c++)
#pragma unroll
    for (int t = 0; t < 2; t++)
      h[c][t] = __builtin_amdgcn_mfma_f32_16x16x32_bf16(w1r[t], bb[c], h[c][t], 0, 0, 0);
#pragma unroll
  for (int c = 0; c < 4; c++)
#pragma unroll
    for (int t = 0; t < 2; t++)
      *(bf16x4*)(Bb + aoff(c * 16 + col, (2 * w + t) * 32 + krow * 8)) = relu_pack(h[c][t]);

  wg_sync();

  // layer2 -> A
#pragma unroll
  for (int c = 0; c < 4; c++)
#pragma unroll
    for (int t = 0; t < 2; t++) h[c][t] = b2c[t];
#pragma unroll
  for (int kt = 0; kt < 4; kt++) {
#pragma unroll
    for (int c = 0; c < 4; c++)
      bb[c] = *(const bf16x8*)(Bb + aoff(c * 16 + col, kt * 64 + krow * 16));
#pragma unroll
    for (int c = 0; c < 4; c++)
#pragma unroll
      for (int t = 0; t < 2; t++)
        h[c][t] = __builtin_amdgcn_mfma_f32_16x16x32_bf16(w2r[kt][t], bb[c], h[c][t], 0, 0, 0);
  }
#pragma unroll
  for (int c = 0; c < 4; c++)
#pragma unroll
    for (int t = 0; t < 2; t++)
      *(bf16x4*)(Ab + aoff(c * 16 + col, (2 * w + t) * 32 + krow * 8)) = relu_pack(h[c][t]);

  wg_sync();

  // layer3 -> B
#pragma unroll
  for (int c = 0; c < 4; c++)
#pragma unroll
    for (int t = 0; t < 2; t++) h[c][t] = b3c[t];
#pragma unroll
  for (int kt = 0; kt < 4; kt++) {
#pragma unroll
    for (int c = 0; c < 4; c++)
      bb[c] = *(const bf16x8*)(Ab + aoff(c * 16 + col, kt * 64 + krow * 16));
#pragma unroll
    for (int c = 0; c < 4; c++)
#pragma unroll
      for (int t = 0; t < 2; t++)
        h[c][t] = __builtin_amdgcn_mfma_f32_16x16x32_bf16(w3r[kt][t], bb[c], h[c][t], 0, 0, 0);
  }
#pragma unroll
  for (int c = 0; c < 4; c++)
#pragma unroll
    for (int t = 0; t < 2; t++)
      *(bf16x4*)(Bb + aoff(c * 16 + col, (2 * w + t) * 32 + krow * 8)) = relu_pack(h[c][t]);

  wg_sync();

  // layer4 (128 -> 1)
  f32x4 o = {0.f, 0.f, 0.f, 0.f};
  if (krow == 0) o[0] = b4s;
#pragma unroll
  for (int kt = 0; kt < 4; kt++) {
    bf16x8 bq = *(const bf16x8*)(Bb + aoff(w * 16 + col, kt * 64 + krow * 16));
    o = __builtin_amdgcn_mfma_f32_16x16x32_bf16(w4r[kt], bq, o, 0, 0, 0);
  }

  if (krow == 0) {
    int i3 = tile * 64 + w * 16 + col;
    if (i3 < n) out[i3] = y_prev[i3] + o[0];
  }
}

// ================= host =================
extern "C" void kernel_launch(void* const* d_in, const int* in_sizes, int n_in, void* d_out,
                              int out_size, void* d_ws, size_t ws_size, hipStream_t stream) {
  const float* Xc = (const float*)d_in[0];
  const float* y_prev = (const float*)d_in[1];
  const int* edge = (const int*)d_in[2];
  const float* ew1 = (const float*)d_in[4];
  const float* eb1 = (const float*)d_in[5];
  const float* ew2 = (const float*)d_in[6];
  const float* eb2 = (const float*)d_in[7];
  const float* ew3 = (const float*)d_in[8];
  const float* eb3 = (const float*)d_in[9];
  const float* nw1 = (const float*)d_in[10];
  const float* nb1 = (const float*)d_in[11];
  const float* nw2 = (const float*)d_in[12];
  const float* nb2 = (const float*)d_in[13];
  const float* nw3 = (const float*)d_in[14];
  const float* nb3 = (const float*)d_in[15];
  const float* dw1 = (const float*)d_in[16];
  const float* db1 = (const float*)d_in[17];
  const float* dw2 = (const float*)d_in[18];
  const float* db2 = (const float*)d_in[19];
  const float* dw3 = (const float*)d_in[20];
  const float* db3 = (const float*)d_in[21];
  const float* dw4 = (const float*)d_in[22];
  const float* db4 = (const float*)d_in[23];

  int n = in_sizes[0] / 6;
  int E = in_sizes[2] / 2;
  const int* srcp = edge;
  const int* dstp = edge + E;

  __bf16* wb = (__bf16*)d_ws;
  float* fbase = (float*)((char*)d_ws + (size_t)WB_TOTAL * 2);
  size_t na = ((size_t)n + 3) & ~(size_t)3;
  float* x4 = fbase;                 // na
  float* invdeg = fbase + na;        // na
  int* rp = (int*)(fbase + 2 * na);  // na + 8 (starts, rp[n]=E)
  int* bcnt = rp + na + 8;           // 1056
  int* bstart = bcnt + 1056;         // 1056 (pristine bucket starts + sentinel)
  int* cur = bstart + 1056;          // 1024 (mutated by k_bin)
  int* srcS = cur + 1024;            // E
  int* dstS = srcS + E;              // E (aliases eix during sort build)
  float* peS = (float*)(dstS + E);   // 4*E
  float* eaS = peS + 4 * (size_t)E;  // 4*E

  size_t need = (size_t)WB_TOTAL * 2 + (3 * na + 8 + 3136 + 10 * (size_t)E) * 4;
  if (ws_size < need) return;  // workspace too small -> fail loudly

  dim3 B(256);
  int nblk = (n + 255) / 256;            // 196
  int nbkt = (n + BKT_SZ - 1) / BKT_SZ;  // 782 (must be <= 1024)
  int eblk = (E + 8191) / 8192;          // 98
  k_prep<<<dim3((WB_TOTAL + 255) / 256), B, 0, stream>>>(ew1, eb1, ew2, ew3, nw1, nb1, nw2, nw3,
                                                         dw1, db1, dw2, dw3, dw4, wb);
  k_zero<<<dim3(nblk), B, 0, stream>>>(y_prev, x4, bcnt, n, nbkt);
  k_cntb<<<dim3(eblk), B, 0, stream>>>(dstp, bcnt, nbkt, E);
  k_scanb<<<dim3(1), dim3(1024), 0, stream>>>(bcnt, bstart, cur, rp, nbkt, n, E);
  k_bin<<<dim3(eblk), B, 0, stream>>>(dstp, cur, dstS, nbkt, E);
  k_build<<<dim3(nbkt), B, 0, stream>>>(srcp, dstp, Xc, y_prev, bstart, dstS, srcS, dstS, peS,
                                        eaS, rp, invdeg, n);

  int etiles = (E + 63) / 64;
  int vtiles = (n + 63) / 64;
  int egrid = etiles < 768 ? etiles : 768;
  for (int it = 0; it < 3; it++) {
    k_edge<<<dim3(egrid), B, 0, stream>>>(x4, peS, eaS, srcS, dstS, wb + WB_W1E, wb + WB_W2E,
                                          wb + WB_W3E, eb2, eb3, etiles, E);
    k_node<<<dim3(vtiles), B, 0, stream>>>(x4, Xc, eaS, rp, invdeg, wb + WB_W1N, wb + WB_W2N,
                                           wb + WB_W3N, nb2, nb3, n);
  }
  k_dec<<<dim3(vtiles), B, 0, stream>>>(x4, Xc, y_prev, wb + WB_W1D, wb + WB_W2D, wb + WB_W3D,
                                        wb + WB_W4D, db2, db3, db4, (float*)d_out, n);
}